// Round 5
// baseline (225.564 us; speedup 1.0000x reference)
//
#include <hip/hip_runtime.h>
#include <hip/hip_bf16.h>
#include <cstdint>
#include <cstddef>

// Problem constants
#define EE    1024
#define DIN   2048
#define NST   16
#define DTR   64
#define BB_   2
#define LL    1024
#define BL    (BB_*LL)        // 2048 tokens
#define NCHUNK 32
#define CLEN   32             // 1024 / 32
#define RTT   16              // TT rank (all four factor pairs)

typedef unsigned short u16;
typedef unsigned int   u32;

// ---------------- workspace layout (in floats) ----------------
static constexpr size_t OFF_WINT  = 0;                   // bf16 [4096][1024]
static constexpr size_t OFF_WOUTT = 2097152;             // bf16 [1024][2048]
static constexpr size_t OFF_WXT   = 3145728;             // bf16 [128][2048] rows>=96 zero
static constexpr size_t OFF_WDTT  = 3276800;             // bf16 [2048][64]
static constexpr size_t OFF_A2T   = 3342336;             // f32  [16][2048]
static constexpr size_t OFF_XB    = 3375104;             // bf16 [2048][1024]
static constexpr size_t OFF_XZB   = 4423680;             // bf16 [2048][4096]
static constexpr size_t OFF_YB    = 8617984;             // bf16 [2048][2048]
static constexpr size_t OFF_PART  = 10715136;            // f32  GEMM2 partials [8][2048][96]
static constexpr size_t OFF_DTBC  = 14909440;            // f32  [2048][96]
static constexpr size_t OFF_DTUNB = 15106048;            // bf16 [2048][64]
static constexpr size_t OFF_DTB   = 15171584;            // bf16 [2048][2048] (dt)
static constexpr size_t OFF_YSB   = 17268736;            // bf16 [2048][2048]
static constexpr size_t OFF_HC    = 19365888;            // f32  [2*32][16][2048] carries
static constexpr size_t OFF_SDT   = 21463040;            // f32  [2*32][2048]

// ---------------- helpers ----------------
__device__ __forceinline__ u16 f2bf(float f) {   // RNE f32->bf16
    u32 u = __float_as_uint(f);
    u += 0x7fffu + ((u >> 16) & 1u);
    return (u16)(u >> 16);
}
__device__ __forceinline__ float bf2f(u16 v) {
    return __uint_as_float((u32)v << 16);
}

__device__ __forceinline__ void async_copy16(const void* g, void* l) {
    __builtin_amdgcn_global_load_lds((const __attribute__((address_space(1))) u32*)g,
                                     (__attribute__((address_space(3))) u32*)l,
                                     16, 0, 0);
}

__device__ __forceinline__ float softplusf(float v) {
    return fmaxf(v, 0.f) + log1pf(__expf(-fabsf(v)));
}

// ---------------- fused prep: 4 TT builds + x->bf16 + A2t + zero(d_out) ----------------
// 2 columns per block (halves block count: gather-latency-bound, not FLOP-bound)
__device__ void tt_part(const float* __restrict__ g1, const float* __restrict__ g2,
                        u16* __restrict__ Wt, int m1, int n1, int m2, int n2,
                        int c, int crows, float* g1col, float* g2col)
{
    const int rowsW = m1 * m2;
    if (c >= crows) {                      // zero padding rows (GEMM2 N-pad)
        for (int k = threadIdx.x; k < rowsW; k += 256)
            Wt[(size_t)c * rowsW + k] = 0;
        return;
    }
    __syncthreads();                       // protect smem from previous call's readers
    const int i = c / n2;
    const int j = c - i * n2;

    for (int e = threadIdx.x; e < m1 * RTT; e += 256) {
        const int a = e >> 4, rr = e & 15;
        g1col[e] = g1[(size_t)(a * n1 + i) * RTT + rr];
    }
    for (int e = threadIdx.x; e < RTT * m2; e += 256) {
        const int rr = e / m2, bb = e - rr * m2;
        g2col[e] = g2[(size_t)(rr * m2 + bb) * n2 + j];
    }
    __syncthreads();

    for (int k = threadIdx.x; k < rowsW; k += 256) {
        const int a  = k / m2;
        const int bb = k - a * m2;
        const float* gp = g1col + a * RTT;
        float s = 0.f;
        #pragma unroll
        for (int rr = 0; rr < RTT; ++rr)
            s = fmaf(gp[rr], g2col[rr * m2 + bb], s);
        Wt[(size_t)c * rowsW + k] = f2bf(s);
    }
}

__global__ __launch_bounds__(256) void mega_prep(
    const float* __restrict__ in_g1, const float* __restrict__ in_g2, u16* __restrict__ W_inT,
    const float* __restrict__ out_g1, const float* __restrict__ out_g2, u16* __restrict__ W_outT,
    const float* __restrict__ x_g1, const float* __restrict__ x_g2, u16* __restrict__ W_xT,
    const float* __restrict__ dt_g1, const float* __restrict__ dt_g2, u16* __restrict__ W_dtT,
    const float* __restrict__ x, u16* __restrict__ xb,
    const float* __restrict__ A_log, float* __restrict__ A2t,
    float* __restrict__ out0)
{
    __shared__ float g1col[32 * RTT];
    __shared__ float g2col[RTT * 64];
    const int blk = blockIdx.x;
    if (blk < 2048) {                                      // W_inT: 4096 cols
        const int c = blk * 2;
        tt_part(in_g1, in_g2, W_inT, 32, 64, 32, 64, c,     4096, g1col, g2col);
        tt_part(in_g1, in_g2, W_inT, 32, 64, 32, 64, c + 1, 4096, g1col, g2col);
    } else if (blk < 2560) {                               // W_outT: 1024 cols
        const int c = (blk - 2048) * 2;
        tt_part(out_g1, out_g2, W_outT, 32, 32, 64, 32, c,     1024, g1col, g2col);
        tt_part(out_g1, out_g2, W_outT, 32, 32, 64, 32, c + 1, 1024, g1col, g2col);
    } else if (blk < 2624) {                               // W_xT: 128 cols (96 real)
        const int c = (blk - 2560) * 2;
        tt_part(x_g1, x_g2, W_xT, 32, 8, 64, 12, c,     96, g1col, g2col);
        tt_part(x_g1, x_g2, W_xT, 32, 8, 64, 12, c + 1, 96, g1col, g2col);
    } else if (blk < 3648) {                               // W_dtT: 2048 cols
        const int c = (blk - 2624) * 2;
        tt_part(dt_g1, dt_g2, W_dtT, 8, 32, 8, 64, c,     2048, g1col, g2col);
        tt_part(dt_g1, dt_g2, W_dtT, 8, 32, 8, 64, c + 1, 2048, g1col, g2col);
    } else if (blk < 4672) {                               // x -> bf16 + zero d_out
        const int i0 = (blk - 3648) * 512 + threadIdx.x;
        const float4 z4 = {0.f, 0.f, 0.f, 0.f};
        #pragma unroll
        for (int s = 0; s < 2; ++s) {
            const int i = i0 + s * 256;
            float4 v = ((const float4*)x)[i];
            ushort4 o;
            o.x = f2bf(v.x); o.y = f2bf(v.y); o.z = f2bf(v.z); o.w = f2bf(v.w);
            ((ushort4*)xb)[i] = o;
            ((float4*)out0)[i] = z4;       // BL*EE/4 float4s == same index space
        }
    } else {                                               // A2t (128 blocks)
        const int idx = (blk - 4672) * 256 + threadIdx.x;  // over DIN*NST
        const int d = idx >> 4, n = idx & 15;
        A2t[n * DIN + d] = -expf(A_log[idx]);
    }
}

// ---------------- bf16 MFMA GEMM (templated BN / BK / output mode) ----------------
// C = A[M,K] @ Bt[N,K]^T. A/Bt row-major bf16 (row stride K). BM=128.
// XOR swizzle on 16B k-slots: LDS pos s holds global slot s^((r>>1)&(SLOT-1)).
// Split-K: blockIdx.z picks K-chunk + output plane (czstride).
// OUT: 0 = f32 store (ncols-guarded), 1 = bf16, 2 = softplus+bf16,
//      3 = f32 atomicAdd into Cout (2-way split-K: commutative -> bitwise-stable).
typedef __attribute__((ext_vector_type(8))) short bf16x8;
typedef __attribute__((ext_vector_type(4))) float floatx4;
typedef __attribute__((ext_vector_type(8))) unsigned short ushortx8;

template<int BN, int BK, int OUT>
__global__ __launch_bounds__(256) void gemm_bf16(
    const u16* __restrict__ A, const u16* __restrict__ Bt, void* __restrict__ Cout,
    int K, int ldc, int kchunk, size_t czstride, int ncols)
{
    constexpr int BM   = 128;
    constexpr int NT   = BN / 32;          // n-tiles per wave
    constexpr int SLOT = BK / 8;           // 16B slots per LDS row
    constexpr int CR   = 64 / SLOT;        // rows per copy instruction
    constexpr int NACH = BM / CR / 4;      // A copies per wave
    constexpr int NBCH = BN / CR / 4;      // B copies per wave
    constexpr int KG   = BK / 32;          // MFMA k-groups per step
    __shared__ __align__(16) u16 smem[BM * BK + BN * BK];
    u16* As = smem;
    u16* Bs = smem + BM * BK;

    const int tid  = threadIdx.x;
    const int w    = tid >> 6;
    const int lane = tid & 63;
    const int wm   = w & 1, wn = w >> 1;
    const int row0 = blockIdx.y * BM;
    const int col0 = blockIdx.x * BN;
    const int kbeg = blockIdx.z * kchunk;

    const int srow = lane / SLOT;
    const int kqp  = lane % SLOT;
    const u16* ga[NACH]; u16* la[NACH];
    #pragma unroll
    for (int i = 0; i < NACH; ++i) {
        const int c  = w * NACH + i;
        const int r  = c * CR + srow;
        const int kq = kqp ^ ((r >> 1) & (SLOT - 1));
        ga[i] = A + (size_t)(row0 + r) * K + kbeg + kq * 8;
        la[i] = &As[c * CR * BK];
    }
    const u16* gb[NBCH]; u16* lb[NBCH];
    #pragma unroll
    for (int i = 0; i < NBCH; ++i) {
        const int c  = w * NBCH + i;
        const int r  = c * CR + srow;
        const int kq = kqp ^ ((r >> 1) & (SLOT - 1));
        gb[i] = Bt + (size_t)(col0 + r) * K + kbeg + kq * 8;
        lb[i] = &Bs[c * CR * BK];
    }

    const int q = lane >> 4, l15 = lane & 15;
    int a_off[4][KG], b_off[NT][KG];
    #pragma unroll
    for (int mt = 0; mt < 4; ++mt) {
        const int r = wm * 64 + mt * 16 + l15;
        const int m = (r >> 1) & (SLOT - 1);
        #pragma unroll
        for (int kk = 0; kk < KG; ++kk)
            a_off[mt][kk] = r * BK + ((kk * 4 + q) ^ m) * 8;
    }
    #pragma unroll
    for (int nt = 0; nt < NT; ++nt) {
        const int r = wn * (BN / 2) + nt * 16 + l15;
        const int m = (r >> 1) & (SLOT - 1);
        #pragma unroll
        for (int kk = 0; kk < KG; ++kk)
            b_off[nt][kk] = r * BK + ((kk * 4 + q) ^ m) * 8;
    }

    floatx4 acc[4][NT];
    #pragma unroll
    for (int mt = 0; mt < 4; ++mt)
        #pragma unroll
        for (int nt = 0; nt < NT; ++nt)
            acc[mt][nt] = (floatx4){0.f, 0.f, 0.f, 0.f};

    for (int k0 = 0; k0 < kchunk; k0 += BK) {
        #pragma unroll
        for (int i = 0; i < NACH; ++i) { async_copy16(ga[i], la[i]); ga[i] += BK; }
        #pragma unroll
        for (int i = 0; i < NBCH; ++i) { async_copy16(gb[i], lb[i]); gb[i] += BK; }
        __syncthreads();   // drains vmcnt -> tiles ready

        bf16x8 af[4][KG], bfv[NT][KG];
        #pragma unroll
        for (int mt = 0; mt < 4; ++mt)
            #pragma unroll
            for (int kk = 0; kk < KG; ++kk)
                af[mt][kk] = *(const bf16x8*)&As[a_off[mt][kk]];
        #pragma unroll
        for (int nt = 0; nt < NT; ++nt)
            #pragma unroll
            for (int kk = 0; kk < KG; ++kk)
                bfv[nt][kk] = *(const bf16x8*)&Bs[b_off[nt][kk]];

        #pragma unroll
        for (int kk = 0; kk < KG; ++kk)
            #pragma unroll
            for (int mt = 0; mt < 4; ++mt)
                #pragma unroll
                for (int nt = 0; nt < NT; ++nt)
                    acc[mt][nt] = __builtin_amdgcn_mfma_f32_16x16x32_bf16(
                        af[mt][kk], bfv[nt][kk], acc[mt][nt], 0, 0, 0);

        __syncthreads();   // reads done before next stage overwrites
    }

    // epilogue: C/D layout col=lane&15, row=(lane>>4)*4+reg  [verified m89/m91]
    if constexpr (OUT == 0) {
        #pragma unroll
        for (int mt = 0; mt < 4; ++mt) {
            const int row = row0 + wm * 64 + mt * 16 + q * 4;
            #pragma unroll
            for (int nt = 0; nt < NT; ++nt) {
                const int col = col0 + wn * (BN / 2) + nt * 16 + l15;
                if (col < ncols) {
                    #pragma unroll
                    for (int r = 0; r < 4; ++r)
                        ((float*)Cout)[(size_t)blockIdx.z * czstride + (size_t)(row + r) * ldc + col] = acc[mt][nt][r];
                }
            }
        }
    } else if constexpr (OUT == 3) {
        #pragma unroll
        for (int mt = 0; mt < 4; ++mt) {
            const int row = row0 + wm * 64 + mt * 16 + q * 4;
            #pragma unroll
            for (int nt = 0; nt < NT; ++nt) {
                const int col = col0 + wn * (BN / 2) + nt * 16 + l15;
                #pragma unroll
                for (int r = 0; r < 4; ++r)
                    atomicAdd(&((float*)Cout)[(size_t)(row + r) * ldc + col], acc[mt][nt][r]);
            }
        }
    } else {
        // stage to LDS with a 16B-granular XOR swizzle, then coalesced copy-out
        u16* cst = smem;                                 // BM*BN u16 fits (BN<=128)
        #pragma unroll
        for (int mt = 0; mt < 4; ++mt) {
            #pragma unroll
            for (int nt = 0; nt < NT; ++nt) {
                const int lc = wn * (BN / 2) + nt * 16 + l15;
                #pragma unroll
                for (int r = 0; r < 4; ++r) {
                    float v = acc[mt][nt][r];
                    if constexpr (OUT == 2) v = softplusf(v);
                    const int lr = wm * 64 + mt * 16 + q * 4 + r;
                    cst[lr * BN + (lc ^ ((lr & (BN / 8 - 1)) << 3))] = f2bf(v);
                }
            }
        }
        __syncthreads();
        constexpr int C8 = BN / 8;
        for (int i = tid; i < BM * C8; i += 256) {
            const int r  = i / C8;
            const int c8 = i % C8;
            const int gc = col0 + c8 * 8;
            if (gc < ncols)
                *(ushortx8*)&((u16*)Cout)[(size_t)(row0 + r) * ldc + gc] =
                    *(const ushortx8*)&cst[r * BN + ((c8 * 8) ^ ((r & (BN / 8 - 1)) << 3))];
        }
    }
}

// ---------------- deep-pipelined GEMM for GEMM1 (T2+T3+T4+T5) ----------------
// 128x256 tile, 8 waves (2Mx4N, 64x64 per wave), BK=64, TRIPLE-buffered LDS
// (144 KiB). Counted s_waitcnt vmcnt(6) at tile boundaries (never 0 in the
// main loop); per K-tile 2 phases of {8 ds_read ; 3 prefetch ; barrier ;
// lgkmcnt(0) ; setprio(1) ; 16 MFMA ; setprio(0) ; barrier}.
__global__ __launch_bounds__(512, 2) void gemm_bf16_dp(
    const u16* __restrict__ A, const u16* __restrict__ Bt, u16* __restrict__ Cout,
    int K, int ldc)
{
    constexpr int BM   = 128;
    constexpr int BN   = 256;
    constexpr int BK   = 64;
    constexpr int SLOT = BK / 8;           // 8 16B slots per row
    constexpr int CR   = 64 / SLOT;        // 8 rows per copy instruction
    constexpr int NACH = BM / CR / 8;      // 2 A copies per wave
    constexpr int NBCH = BN / CR / 8;      // 4 B copies per wave
    constexpr int AST  = BM * BK;          // u16 per A buffer (16 KiB)
    constexpr int BST  = BN * BK;          // u16 per B buffer (32 KiB)

    __shared__ __align__(16) u16 As[3 * AST];
    __shared__ __align__(16) u16 Bs[3 * BST];            // total 144 KiB

    const int tid  = threadIdx.x;
    const int w    = tid >> 6;
    const int lane = tid & 63;
    const int wm   = w & 1;                // 2 waves over M
    const int wn   = w >> 1;               // 4 waves over N
    const int row0 = blockIdx.y * BM;
    const int col0 = blockIdx.x * BN;

    const int srow = lane / SLOT;
    const int kqp  = lane % SLOT;
    const u16* ga[NACH]; int laA[NACH];
    #pragma unroll
    for (int i = 0; i < NACH; ++i) {
        const int c  = w * NACH + i;       // 0..15
        const int r  = c * CR + srow;
        const int kq = kqp ^ ((r >> 1) & (SLOT - 1));
        ga[i]  = A + (size_t)(row0 + r) * K + kq * 8;
        laA[i] = c * CR * BK;
    }
    const u16* gb[NBCH]; int laB[NBCH];
    #pragma unroll
    for (int i = 0; i < NBCH; ++i) {
        const int c  = w * NBCH + i;       // 0..31
        const int r  = c * CR + srow;
        const int kq = kqp ^ ((r >> 1) & (SLOT - 1));
        gb[i]  = Bt + (size_t)(col0 + r) * K + kq * 8;
        laB[i] = c * CR * BK;
    }

    const int q = lane >> 4, l15 = lane & 15;
    int a_off[4][2], b_off[4][2];
    #pragma unroll
    for (int mt = 0; mt < 4; ++mt) {
        const int r = wm * 64 + mt * 16 + l15;
        const int m = (r >> 1) & (SLOT - 1);
        #pragma unroll
        for (int kk = 0; kk < 2; ++kk)
            a_off[mt][kk] = r * BK + ((kk * 4 + q) ^ m) * 8;
    }
    #pragma unroll
    for (int nt = 0; nt < 4; ++nt) {
        const int r = wn * 64 + nt * 16 + l15;
        const int m = (r >> 1) & (SLOT - 1);
        #pragma unroll
        for (int kk = 0; kk < 2; ++kk)
            b_off[nt][kk] = r * BK + ((kk * 4 + q) ^ m) * 8;
    }

    floatx4 acc[4][4];
    #pragma unroll
    for (int mt = 0; mt < 4; ++mt)
        #pragma unroll
        for (int nt = 0; nt < 4; ++nt)
            acc[mt][nt] = (floatx4){0.f, 0.f, 0.f, 0.f};

    const int NTILES = K / BK;             // >= 2 required (GEMM1: 16)

    // prologue: stage K-tiles 0 and 1 into bufs 0,1 (6 loads/wave each)
    #pragma unroll
    for (int i = 0; i < NACH; ++i) { async_copy16(ga[i], &As[0 * AST + laA[i]]); ga[i] += BK; }
    #pragma unroll
    for (int i = 0; i < NBCH; ++i) { async_copy16(gb[i], &Bs[0 * BST + laB[i]]); gb[i] += BK; }
    #pragma unroll
    for (int i = 0; i < NACH; ++i) { async_copy16(ga[i], &As[1 * AST + laA[i]]); ga[i] += BK; }
    #pragma unroll
    for (int i = 0; i < NBCH; ++i) { async_copy16(gb[i], &Bs[1 * BST + laB[i]]); gb[i] += BK; }
    __builtin_amdgcn_sched_barrier(0);
    asm volatile("s_waitcnt vmcnt(6)" ::: "memory");   // tile0 landed; tile1 in flight
    __builtin_amdgcn_s_barrier();
    __builtin_amdgcn_sched_barrier(0);

    int cur = 0, nxt = 2;
    for (int t = 0; t < NTILES; ++t) {
        const bool pf = (t + 2 < NTILES);
        const u16* Ac = &As[cur * AST];
        const u16* Bc = &Bs[cur * BST];
        u16* An = &As[nxt * AST];
        u16* Bn = &Bs[nxt * BST];

        bf16x8 af[4], bfv[4];

        // ---------- phase A: kk = 0 ----------
        #pragma unroll
        for (int mt = 0; mt < 4; ++mt) af[mt]  = *(const bf16x8*)&Ac[a_off[mt][0]];
        #pragma unroll
        for (int nt = 0; nt < 4; ++nt) bfv[nt] = *(const bf16x8*)&Bc[b_off[nt][0]];
        if (pf) {
            async_copy16(ga[0], &An[laA[0]]);
            async_copy16(ga[1], &An[laA[1]]);
            async_copy16(gb[0], &Bn[laB[0]]);
        }
        __builtin_amdgcn_sched_barrier(0);
        __builtin_amdgcn_s_barrier();
        asm volatile("s_waitcnt lgkmcnt(0)" ::: "memory");
        __builtin_amdgcn_sched_barrier(0);
        __builtin_amdgcn_s_setprio(1);
        #pragma unroll
        for (int mt = 0; mt < 4; ++mt)
            #pragma unroll
            for (int nt = 0; nt < 4; ++nt)
                acc[mt][nt] = __builtin_amdgcn_mfma_f32_16x16x32_bf16(
                    af[mt], bfv[nt], acc[mt][nt], 0, 0, 0);
        __builtin_amdgcn_s_setprio(0);
        __builtin_amdgcn_sched_barrier(0);
        __builtin_amdgcn_s_barrier();
        __builtin_amdgcn_sched_barrier(0);

        // ---------- phase B: kk = 1 ----------
        #pragma unroll
        for (int mt = 0; mt < 4; ++mt) af[mt]  = *(const bf16x8*)&Ac[a_off[mt][1]];
        #pragma unroll
        for (int nt = 0; nt < 4; ++nt) bfv[nt] = *(const bf16x8*)&Bc[b_off[nt][1]];
        if (pf) {
            async_copy16(gb[1], &Bn[laB[1]]);
            async_copy16(gb[2], &Bn[laB[2]]);
            async_copy16(gb[3], &Bn[laB[3]]);
            #pragma unroll
            for (int i = 0; i < NACH; ++i) ga[i] += BK;
            #pragma unroll
            for (int i = 0; i < NBCH; ++i) gb[i] += BK;
        }
        __builtin_amdgcn_sched_barrier(0);
        __builtin_amdgcn_s_barrier();
        asm volatile("s_waitcnt lgkmcnt(0)" ::: "memory");
        __builtin_amdgcn_sched_barrier(0);
        __builtin_amdgcn_s_setprio(1);
        #pragma unroll
        for (int mt = 0; mt < 4; ++mt)
            #pragma unroll
            for (int nt = 0; nt < 4; ++nt)
                acc[mt][nt] = __builtin_amdgcn_mfma_f32_16x16x32_bf16(
                    af[mt], bfv[nt], acc[mt][nt], 0, 0, 0);
        __builtin_amdgcn_s_setprio(0);
        __builtin_amdgcn_sched_barrier(0);
        // counted boundary wait: oldest 6 (tile t+1) complete, newest 6
        // (tile t+2) stay in flight. Last two tiles: drain.
        if (pf) asm volatile("s_waitcnt vmcnt(6)" ::: "memory");
        else    asm volatile("s_waitcnt vmcnt(0)" ::: "memory");
        __builtin_amdgcn_s_barrier();
        __builtin_amdgcn_sched_barrier(0);

        cur = (cur == 2) ? 0 : cur + 1;
        nxt = (nxt == 2) ? 0 : nxt + 1;
    }

    // epilogue: stage C-tile (128x256 bf16 = 64 KiB) into Bs, copy out ushort8.
    // swizzle: col ^ ((row & 31) << 3) -- 16B-granular, bijective per row.
    u16* cst = Bs;
    #pragma unroll
    for (int mt = 0; mt < 4; ++mt) {
        #pragma unroll
        for (int nt = 0; nt < 4; ++nt) {
            const int lc = wn * 64 + nt * 16 + l15;
            #pragma unroll
            for (int r = 0; r < 4; ++r) {
                const int lr = wm * 64 + mt * 16 + q * 4 + r;
                cst[lr * 256 + (lc ^ ((lr & 31) << 3))] = f2bf(acc[mt][nt][r]);
            }
        }
    }
    __syncthreads();
    for (int i = tid; i < 128 * 32; i += 512) {
        const int r  = i >> 5;
        const int c8 = i & 31;
        *(ushortx8*)&Cout[(size_t)(row0 + r) * ldc + col0 + c8 * 8] =
            *(const ushortx8*)&cst[r * 256 + ((c8 * 8) ^ ((r & 31) << 3))];
    }
}

// reduce GEMM2 split-K partials (z=8, stride 96): dtBC[row][col] = sum_z part[z][row][col];
// also emit dt_un (cols 0..63) as bf16 for GEMM3.
__global__ __launch_bounds__(256) void reduce_dtbc(
    const float* __restrict__ part, float* __restrict__ dtBC, u16* __restrict__ dtun_b)
{
    int idx = blockIdx.x * 256 + threadIdx.x;
    if (idx >= BL * 96) return;
    const int row = idx / 96;
    const int col = idx - row * 96;
    float s = 0.f;
    #pragma unroll
    for (int z = 0; z < 8; ++z)
        s += part[(size_t)z * BL * 96 + idx];
    dtBC[idx] = s;
    if (col < 64) dtun_b[(size_t)row * 64 + col] = f2bf(s);
}

// ---------------- conv (depthwise K=4, SAME pad_lo=1) + SiLU + gate ----------------
// 4 consecutive tokens per thread, 7-row rolling window in registers:
// reads 7 conv rows + 4 z rows per 4 outputs (vs 16+4 at 1 token/thread whose
// neighbor re-reads cross XCDs and miss L2). Same FMA count, ~0.6x traffic.
__global__ __launch_bounds__(256) void conv_gate(
    const u16* __restrict__ xzb, const float* __restrict__ filt,
    const float* __restrict__ bias, u16* __restrict__ yb)
{
    const int idx = blockIdx.x * 256 + threadIdx.x;   // over (BL/4)*(DIN/8)
    constexpr int ND8 = DIN / 8;                      // 256: one block = one t4 row
    const int t4 = idx / ND8;
    const int d  = (idx - t4 * ND8) * 8;
    const int b  = t4 >> 8;                           // LL/4 = 256 groups per batch
    const int t0 = (t4 & 255) * 4;

    float ff[4][8];
    #pragma unroll
    for (int k = 0; k < 4; ++k)
        #pragma unroll
        for (int j = 0; j < 8; ++j)
            ff[k][j] = filt[(size_t)k * DIN + d + j];

    float acc[4][8];
    #pragma unroll
    for (int tt = 0; tt < 4; ++tt)
        #pragma unroll
        for (int j = 0; j < 8; ++j)
            acc[tt][j] = bias[d + j];

    #pragma unroll
    for (int s = 0; s < 7; ++s) {
        const int ri = t0 - 1 + s;
        if ((unsigned)ri < (unsigned)LL) {
            const ushortx8 xc = *(const ushortx8*)(xzb + (size_t)(b * LL + ri) * (2 * DIN) + d);
            float xf[8];
            #pragma unroll
            for (int j = 0; j < 8; ++j) xf[j] = bf2f(xc[j]);
            #pragma unroll
            for (int tt = 0; tt < 4; ++tt) {
                const int k = s - tt;                 // tap index (compile-time after unroll)
                if (0 <= k && k < 4) {
                    #pragma unroll
                    for (int j = 0; j < 8; ++j)
                        acc[tt][j] = fmaf(xf[j], ff[k][j], acc[tt][j]);
                }
            }
        }
    }
    #pragma unroll
    for (int tt = 0; tt < 4; ++tt) {
        const int t = t0 + tt;
        const ushortx8 z = *(const ushortx8*)(xzb + (size_t)(b * LL + t) * (2 * DIN) + DIN + d);
        ushortx8 o;
        #pragma unroll
        for (int j = 0; j < 8; ++j)
            o[j] = f2bf(acc[tt][j] / (1.f + __expf(-acc[tt][j])) * bf2f(z[j]));
        *(ushortx8*)(yb + (size_t)(b * LL + t) * DIN + d) = o;
    }
}

// ---------------- SSM chunked scan (dt and u in bf16; NCHUNK=32) ----------------
__global__ __launch_bounds__(256) void scan_phase_a(
    const u16* __restrict__ dt, const u16* __restrict__ u,
    const float* __restrict__ dtBC, const float* __restrict__ A2t,
    float* __restrict__ hend, float* __restrict__ sdtbuf)
{
    const int d = blockIdx.x * 256 + threadIdx.x;
    const int c = blockIdx.y;
    const int b = blockIdx.z;

    __shared__ float Bs[CLEN][NST];
    for (int e = threadIdx.x; e < CLEN * NST; e += 256) {
        const int tl = e >> 4, n = e & 15;
        Bs[tl][n] = dtBC[(size_t)(b * LL + c * CLEN + tl) * 96 + 64 + n];
    }
    __syncthreads();

    float A2r[NST];
    #pragma unroll
    for (int n = 0; n < NST; ++n) A2r[n] = A2t[n * DIN + d];

    float h[NST] = {};
    float sdt = 0.f;
    const size_t tbase = (size_t)(b * LL + c * CLEN) * DIN + d;
    for (int tl = 0; tl < CLEN; ++tl) {
        const float dtv = bf2f(dt[tbase + (size_t)tl * DIN]);
        const float uv  = bf2f(u [tbase + (size_t)tl * DIN]);
        sdt += dtv;
        const float cu = dtv * uv;
        #pragma unroll
        for (int n = 0; n < NST; ++n) {
            const float a = __expf(A2r[n] * dtv);
            h[n] = fmaf(a, h[n], cu * Bs[tl][n]);
        }
    }
    const int cb = b * NCHUNK + c;
    #pragma unroll
    for (int n = 0; n < NST; ++n)
        hend[((size_t)cb * NST + n) * DIN + d] = h[n];
    sdtbuf[(size_t)cb * DIN + d] = sdt;
}

__global__ __launch_bounds__(256) void scan_phase_b(
    const float* __restrict__ A2t, const float* __restrict__ sdtbuf,
    float* __restrict__ hcarry)
{
    const int idx = blockIdx.x * 256 + threadIdx.x;  // b*32768 + n*2048 + d
    if (idx >= BB_ * NST * DIN) return;
    const int d = idx & (DIN - 1);
    const int n = (idx >> 11) & 15;
    const int b = idx >> 15;
    const float A2 = A2t[n * DIN + d];
    float h = 0.f;
    for (int c = 0; c < NCHUNK; ++c) {
        const int cb = b * NCHUNK + c;
        const size_t off = ((size_t)cb * NST + n) * DIN + d;
        const float he = hcarry[off];
        const float pa = __expf(A2 * sdtbuf[(size_t)cb * DIN + d]);
        hcarry[off] = h;
        h = fmaf(pa, h, he);
    }
}

__global__ __launch_bounds__(256) void scan_phase_c(
    const u16* __restrict__ dt, const u16* __restrict__ u,
    const float* __restrict__ dtBC, const float* __restrict__ A2t,
    const float* __restrict__ hinit, const float* __restrict__ Dp,
    u16* __restrict__ ysb)
{
    const int d = blockIdx.x * 256 + threadIdx.x;
    const int c = blockIdx.y;
    const int b = blockIdx.z;

    __shared__ float Bs[CLEN][NST];
    __shared__ float Cs[CLEN][NST];
    for (int e = threadIdx.x; e < CLEN * NST; e += 256) {
        const int tl = e >> 4, n = e & 15;
        const size_t base = (size_t)(b * LL + c * CLEN + tl) * 96;
        Bs[tl][n] = dtBC[base + 64 + n];
        Cs[tl][n] = dtBC[base + 80 + n];
    }
    __syncthreads();

    float A2r[NST], h[NST];
    const int cb = b * NCHUNK + c;
    #pragma unroll
    for (int n = 0; n < NST; ++n) {
        A2r[n] = A2t[n * DIN + d];
        h[n]   = hinit[((size_t)cb * NST + n) * DIN + d];
    }
    const float Dv = Dp[d];

    const size_t tbase = (size_t)(b * LL + c * CLEN) * DIN + d;
    for (int tl = 0; tl < CLEN; ++tl) {
        const float dtv = bf2f(dt[tbase + (size_t)tl * DIN]);
        const float uv  = bf2f(u [tbase + (size_t)tl * DIN]);
        const float cu = dtv * uv;
        float yacc = 0.f;
        #pragma unroll
        for (int n = 0; n < NST; ++n) {
            const float a = __expf(A2r[n] * dtv);
            h[n] = fmaf(a, h[n], cu * Bs[tl][n]);
            yacc = fmaf(h[n], Cs[tl][n], yacc);
        }
        ysb[tbase + (size_t)tl * DIN] = f2bf(fmaf(Dv, uv, yacc));
    }
}

// ---------------- launcher ----------------
extern "C" void kernel_launch(void* const* d_in, const int* in_sizes, int n_in,
                              void* d_out, int out_size, void* d_ws, size_t ws_size,
                              hipStream_t stream)
{
    const float* x       = (const float*)d_in[0];
    const float* in_g1   = (const float*)d_in[1];
    const float* in_g2   = (const float*)d_in[2];
    const float* x_g1    = (const float*)d_in[3];
    const float* x_g2    = (const float*)d_in[4];
    const float* dt_g1   = (const float*)d_in[5];
    const float* dt_g2   = (const float*)d_in[6];
    const float* out_g1  = (const float*)d_in[7];
    const float* out_g2  = (const float*)d_in[8];
    const float* filt    = (const float*)d_in[9];
    const float* bias    = (const float*)d_in[10];
    const float* A_log   = (const float*)d_in[11];
    const float* Dp      = (const float*)d_in[12];

    float* ws     = (float*)d_ws;
    u16*   W_inT  = (u16*)(ws + OFF_WINT);
    u16*   W_outT = (u16*)(ws + OFF_WOUTT);
    u16*   W_xT   = (u16*)(ws + OFF_WXT);
    u16*   W_dtT  = (u16*)(ws + OFF_WDTT);
    float* A2t    = ws + OFF_A2T;
    u16*   xb     = (u16*)(ws + OFF_XB);
    u16*   xzb    = (u16*)(ws + OFF_XZB);
    u16*   yb     = (u16*)(ws + OFF_YB);
    float* part   = ws + OFF_PART;
    float* dtBC   = ws + OFF_DTBC;
    u16*   dtun_b = (u16*)(ws + OFF_DTUNB);
    u16*   dtb    = (u16*)(ws + OFF_DTB);
    u16*   ysb    = (u16*)(ws + OFF_YSB);
    float* hc     = ws + OFF_HC;
    float* sdt    = ws + OFF_SDT;

    // 1) all prep in one launch: W_inT, W_outT, W_xT, W_dtT, x->bf16, A2t,
    //    and zero d_out for GEMM4's atomic accumulation
    mega_prep<<<4800, 256, 0, stream>>>(
        in_g1, in_g2, W_inT, out_g1, out_g2, W_outT,
        x_g1, x_g2, W_xT, dt_g1, dt_g2, W_dtT,
        x, xb, A_log, A2t, (float*)d_out);

    // 2) xz = x @ W_in  (M=2048, N=4096, K=1024) -> bf16 (deep-pipelined)
    gemm_bf16_dp<<<dim3(16, 16, 1), 512, 0, stream>>>(
        xb, W_inT, xzb, EE, 4096);

    // 3) y = silu(conv(xc) + bias) * z  -> bf16, 4 tokens/thread rolling window
    conv_gate<<<(BL / 4) * (DIN / 8) / 256, 256, 0, stream>>>(xzb, filt, bias, yb);

    // 4) dtBC partials = y @ W_x (M=2048, N=128->96, K=2048), split-K z=8, BN=64
    gemm_bf16<64, 64, 0><<<dim3(2, 16, 8), 256, 0, stream>>>(
        yb, W_xT, part, DIN, 96, 256, (size_t)BL * 96, 96);
    reduce_dtbc<<<(BL * 96 + 255) / 256, 256, 0, stream>>>(part, dtBC, dtun_b);

    // 5) dt = softplus(dt_un @ W_dt) (M=2048, N=2048, K=64) -> bf16
    gemm_bf16<64, 64, 2><<<dim3(32, 16, 1), 256, 0, stream>>>(
        dtun_b, W_dtT, dtb, 64, DIN, 64, 0, DIN);

    // 6) SSM chunked scan, NCHUNK=32 (512 blocks = 2/CU)
    scan_phase_a<<<dim3(DIN / 256, NCHUNK, BB_), 256, 0, stream>>>(dtb, yb, dtBC, A2t, hc, sdt);
    scan_phase_b<<<(BB_ * NST * DIN) / 256, 256, 0, stream>>>(A2t, sdt, hc);
    scan_phase_c<<<dim3(DIN / 256, NCHUNK, BB_), 256, 0, stream>>>(dtb, yb, dtBC, A2t, hc, Dp, ysb);

    // 7) out = ssm @ W_out (M=2048, N=1024, K=2048), split-K z=2 (512 blocks),
    //    f32 atomicAdd direct into d_out (2 contributions/elem: commutative ->
    //    bitwise == old reduce; saves 24 MB partial round-trip + 1 launch)
    gemm_bf16<64, 64, 3><<<dim3(16, 16, 2), 256, 0, stream>>>(
        ysb, W_outT, d_out, DIN, EE, EE, 0, EE);
}

// Round 6
// 221.550 us; speedup vs baseline: 1.0181x; 1.0181x over previous
//
#include <hip/hip_runtime.h>
#include <hip/hip_bf16.h>
#include <cstdint>
#include <cstddef>

// Problem constants
#define EE    1024
#define DIN   2048
#define NST   16
#define DTR   64
#define BB_   2
#define LL    1024
#define BL    (BB_*LL)        // 2048 tokens
#define NCHUNK 32
#define CLEN   32             // 1024 / 32
#define RTT   16              // TT rank (all four factor pairs)

typedef unsigned short u16;
typedef unsigned int   u32;

// ---------------- workspace layout (in floats) ----------------
static constexpr size_t OFF_WINT  = 0;                   // bf16 [4096][1024]
static constexpr size_t OFF_WOUTT = 2097152;             // bf16 [1024][2048]
static constexpr size_t OFF_WXT   = 3145728;             // bf16 [128][2048] rows>=96 zero
static constexpr size_t OFF_WDTT  = 3276800;             // bf16 [2048][64]
static constexpr size_t OFF_A2T   = 3342336;             // f32  [16][2048]
static constexpr size_t OFF_XB    = 3375104;             // bf16 [2048][1024]
static constexpr size_t OFF_XZB   = 4423680;             // bf16 [2048][4096]
static constexpr size_t OFF_YB    = 8617984;             // bf16 [2048][2048]
static constexpr size_t OFF_PART  = 10715136;            // f32  GEMM2 partials [8][2048][96]; reused: GEMM4 partials [2][2048][1024]
static constexpr size_t OFF_DTBC  = 14909440;            // f32  [2048][96]
static constexpr size_t OFF_DTUNB = 15106048;            // bf16 [2048][64]
static constexpr size_t OFF_DTB   = 15171584;            // bf16 [2048][2048] (dt)
static constexpr size_t OFF_YSB   = 17268736;            // bf16 [2048][2048]
static constexpr size_t OFF_HC    = 19365888;            // f32  [2*32][16][2048] carries
static constexpr size_t OFF_SDT   = 21463040;            // f32  [2*32][2048]

// ---------------- helpers ----------------
__device__ __forceinline__ u16 f2bf(float f) {   // RNE f32->bf16
    u32 u = __float_as_uint(f);
    u += 0x7fffu + ((u >> 16) & 1u);
    return (u16)(u >> 16);
}
__device__ __forceinline__ float bf2f(u16 v) {
    return __uint_as_float((u32)v << 16);
}

__device__ __forceinline__ void async_copy16(const void* g, void* l) {
    __builtin_amdgcn_global_load_lds((const __attribute__((address_space(1))) u32*)g,
                                     (__attribute__((address_space(3))) u32*)l,
                                     16, 0, 0);
}

__device__ __forceinline__ float softplusf(float v) {
    return fmaxf(v, 0.f) + log1pf(__expf(-fabsf(v)));
}

// ---------------- fused prep: 4 TT builds + x->bf16 + A2t ----------------
// 2 columns per block (halves block count: gather-latency-bound, not FLOP-bound)
__device__ void tt_part(const float* __restrict__ g1, const float* __restrict__ g2,
                        u16* __restrict__ Wt, int m1, int n1, int m2, int n2,
                        int c, int crows, float* g1col, float* g2col)
{
    const int rowsW = m1 * m2;
    if (c >= crows) {                      // zero padding rows (GEMM2 N-pad)
        for (int k = threadIdx.x; k < rowsW; k += 256)
            Wt[(size_t)c * rowsW + k] = 0;
        return;
    }
    __syncthreads();                       // protect smem from previous call's readers
    const int i = c / n2;
    const int j = c - i * n2;

    for (int e = threadIdx.x; e < m1 * RTT; e += 256) {
        const int a = e >> 4, rr = e & 15;
        g1col[e] = g1[(size_t)(a * n1 + i) * RTT + rr];
    }
    for (int e = threadIdx.x; e < RTT * m2; e += 256) {
        const int rr = e / m2, bb = e - rr * m2;
        g2col[e] = g2[(size_t)(rr * m2 + bb) * n2 + j];
    }
    __syncthreads();

    for (int k = threadIdx.x; k < rowsW; k += 256) {
        const int a  = k / m2;
        const int bb = k - a * m2;
        const float* gp = g1col + a * RTT;
        float s = 0.f;
        #pragma unroll
        for (int rr = 0; rr < RTT; ++rr)
            s = fmaf(gp[rr], g2col[rr * m2 + bb], s);
        Wt[(size_t)c * rowsW + k] = f2bf(s);
    }
}

__global__ __launch_bounds__(256) void mega_prep(
    const float* __restrict__ in_g1, const float* __restrict__ in_g2, u16* __restrict__ W_inT,
    const float* __restrict__ out_g1, const float* __restrict__ out_g2, u16* __restrict__ W_outT,
    const float* __restrict__ x_g1, const float* __restrict__ x_g2, u16* __restrict__ W_xT,
    const float* __restrict__ dt_g1, const float* __restrict__ dt_g2, u16* __restrict__ W_dtT,
    const float* __restrict__ x, u16* __restrict__ xb,
    const float* __restrict__ A_log, float* __restrict__ A2t)
{
    __shared__ float g1col[32 * RTT];
    __shared__ float g2col[RTT * 64];
    const int blk = blockIdx.x;
    if (blk < 2048) {                                      // W_inT: 4096 cols
        const int c = blk * 2;
        tt_part(in_g1, in_g2, W_inT, 32, 64, 32, 64, c,     4096, g1col, g2col);
        tt_part(in_g1, in_g2, W_inT, 32, 64, 32, 64, c + 1, 4096, g1col, g2col);
    } else if (blk < 2560) {                               // W_outT: 1024 cols
        const int c = (blk - 2048) * 2;
        tt_part(out_g1, out_g2, W_outT, 32, 32, 64, 32, c,     1024, g1col, g2col);
        tt_part(out_g1, out_g2, W_outT, 32, 32, 64, 32, c + 1, 1024, g1col, g2col);
    } else if (blk < 2624) {                               // W_xT: 128 cols (96 real)
        const int c = (blk - 2560) * 2;
        tt_part(x_g1, x_g2, W_xT, 32, 8, 64, 12, c,     96, g1col, g2col);
        tt_part(x_g1, x_g2, W_xT, 32, 8, 64, 12, c + 1, 96, g1col, g2col);
    } else if (blk < 3648) {                               // W_dtT: 2048 cols
        const int c = (blk - 2624) * 2;
        tt_part(dt_g1, dt_g2, W_dtT, 8, 32, 8, 64, c,     2048, g1col, g2col);
        tt_part(dt_g1, dt_g2, W_dtT, 8, 32, 8, 64, c + 1, 2048, g1col, g2col);
    } else if (blk < 4672) {                               // x -> bf16 (2 float4/thread)
        const int i0 = (blk - 3648) * 512 + threadIdx.x;
        #pragma unroll
        for (int s = 0; s < 2; ++s) {
            const int i = i0 + s * 256;
            float4 v = ((const float4*)x)[i];
            ushort4 o;
            o.x = f2bf(v.x); o.y = f2bf(v.y); o.z = f2bf(v.z); o.w = f2bf(v.w);
            ((ushort4*)xb)[i] = o;
        }
    } else {                                               // A2t (128 blocks)
        const int idx = (blk - 4672) * 256 + threadIdx.x;  // over DIN*NST
        const int d = idx >> 4, n = idx & 15;
        A2t[n * DIN + d] = -expf(A_log[idx]);
    }
}

// ---------------- bf16 MFMA GEMM (templated BN / BK / output mode) ----------------
// C = A[M,K] @ Bt[N,K]^T. A/Bt row-major bf16 (row stride K). BM=128.
// XOR swizzle on 16B k-slots: LDS pos s holds global slot s^((r>>1)&(SLOT-1)).
// Split-K: blockIdx.z picks K-chunk + output plane (czstride).
// OUT: 0 = f32 store (ncols-guarded), 1 = bf16, 2 = softplus+bf16.
// bf16 outputs (OUT 1/2) staged through LDS -> coalesced ushort8 stores.
typedef __attribute__((ext_vector_type(8))) short bf16x8;
typedef __attribute__((ext_vector_type(4))) float floatx4;
typedef __attribute__((ext_vector_type(8))) unsigned short ushortx8;

template<int BN, int BK, int OUT>
__global__ __launch_bounds__(256) void gemm_bf16(
    const u16* __restrict__ A, const u16* __restrict__ Bt, void* __restrict__ Cout,
    int K, int ldc, int kchunk, size_t czstride, int ncols)
{
    constexpr int BM   = 128;
    constexpr int NT   = BN / 32;          // n-tiles per wave
    constexpr int SLOT = BK / 8;           // 16B slots per LDS row
    constexpr int CR   = 64 / SLOT;        // rows per copy instruction
    constexpr int NACH = BM / CR / 4;      // A copies per wave
    constexpr int NBCH = BN / CR / 4;      // B copies per wave
    constexpr int KG   = BK / 32;          // MFMA k-groups per step
    __shared__ __align__(16) u16 smem[BM * BK + BN * BK];
    u16* As = smem;
    u16* Bs = smem + BM * BK;

    const int tid  = threadIdx.x;
    const int w    = tid >> 6;
    const int lane = tid & 63;
    const int wm   = w & 1, wn = w >> 1;
    const int row0 = blockIdx.y * BM;
    const int col0 = blockIdx.x * BN;
    const int kbeg = blockIdx.z * kchunk;

    const int srow = lane / SLOT;
    const int kqp  = lane % SLOT;
    const u16* ga[NACH]; u16* la[NACH];
    #pragma unroll
    for (int i = 0; i < NACH; ++i) {
        const int c  = w * NACH + i;
        const int r  = c * CR + srow;
        const int kq = kqp ^ ((r >> 1) & (SLOT - 1));
        ga[i] = A + (size_t)(row0 + r) * K + kbeg + kq * 8;
        la[i] = &As[c * CR * BK];
    }
    const u16* gb[NBCH]; u16* lb[NBCH];
    #pragma unroll
    for (int i = 0; i < NBCH; ++i) {
        const int c  = w * NBCH + i;
        const int r  = c * CR + srow;
        const int kq = kqp ^ ((r >> 1) & (SLOT - 1));
        gb[i] = Bt + (size_t)(col0 + r) * K + kbeg + kq * 8;
        lb[i] = &Bs[c * CR * BK];
    }

    const int q = lane >> 4, l15 = lane & 15;
    int a_off[4][KG], b_off[NT][KG];
    #pragma unroll
    for (int mt = 0; mt < 4; ++mt) {
        const int r = wm * 64 + mt * 16 + l15;
        const int m = (r >> 1) & (SLOT - 1);
        #pragma unroll
        for (int kk = 0; kk < KG; ++kk)
            a_off[mt][kk] = r * BK + ((kk * 4 + q) ^ m) * 8;
    }
    #pragma unroll
    for (int nt = 0; nt < NT; ++nt) {
        const int r = wn * (BN / 2) + nt * 16 + l15;
        const int m = (r >> 1) & (SLOT - 1);
        #pragma unroll
        for (int kk = 0; kk < KG; ++kk)
            b_off[nt][kk] = r * BK + ((kk * 4 + q) ^ m) * 8;
    }

    floatx4 acc[4][NT];
    #pragma unroll
    for (int mt = 0; mt < 4; ++mt)
        #pragma unroll
        for (int nt = 0; nt < NT; ++nt)
            acc[mt][nt] = (floatx4){0.f, 0.f, 0.f, 0.f};

    for (int k0 = 0; k0 < kchunk; k0 += BK) {
        #pragma unroll
        for (int i = 0; i < NACH; ++i) { async_copy16(ga[i], la[i]); ga[i] += BK; }
        #pragma unroll
        for (int i = 0; i < NBCH; ++i) { async_copy16(gb[i], lb[i]); gb[i] += BK; }
        __syncthreads();   // drains vmcnt -> tiles ready

        bf16x8 af[4][KG], bfv[NT][KG];
        #pragma unroll
        for (int mt = 0; mt < 4; ++mt)
            #pragma unroll
            for (int kk = 0; kk < KG; ++kk)
                af[mt][kk] = *(const bf16x8*)&As[a_off[mt][kk]];
        #pragma unroll
        for (int nt = 0; nt < NT; ++nt)
            #pragma unroll
            for (int kk = 0; kk < KG; ++kk)
                bfv[nt][kk] = *(const bf16x8*)&Bs[b_off[nt][kk]];

        #pragma unroll
        for (int kk = 0; kk < KG; ++kk)
            #pragma unroll
            for (int mt = 0; mt < 4; ++mt)
                #pragma unroll
                for (int nt = 0; nt < NT; ++nt)
                    acc[mt][nt] = __builtin_amdgcn_mfma_f32_16x16x32_bf16(
                        af[mt][kk], bfv[nt][kk], acc[mt][nt], 0, 0, 0);

        __syncthreads();   // reads done before next stage overwrites
    }

    // epilogue: C/D layout col=lane&15, row=(lane>>4)*4+reg  [verified m89/m91]
    if constexpr (OUT == 0) {
        #pragma unroll
        for (int mt = 0; mt < 4; ++mt) {
            const int row = row0 + wm * 64 + mt * 16 + q * 4;
            #pragma unroll
            for (int nt = 0; nt < NT; ++nt) {
                const int col = col0 + wn * (BN / 2) + nt * 16 + l15;
                if (col < ncols) {
                    #pragma unroll
                    for (int r = 0; r < 4; ++r)
                        ((float*)Cout)[(size_t)blockIdx.z * czstride + (size_t)(row + r) * ldc + col] = acc[mt][nt][r];
                }
            }
        }
    } else {
        // stage to LDS with a 16B-granular XOR swizzle, then coalesced copy-out
        u16* cst = smem;                                 // BM*BN u16 fits (BN<=128)
        #pragma unroll
        for (int mt = 0; mt < 4; ++mt) {
            #pragma unroll
            for (int nt = 0; nt < NT; ++nt) {
                const int lc = wn * (BN / 2) + nt * 16 + l15;
                #pragma unroll
                for (int r = 0; r < 4; ++r) {
                    float v = acc[mt][nt][r];
                    if constexpr (OUT == 2) v = softplusf(v);
                    const int lr = wm * 64 + mt * 16 + q * 4 + r;
                    cst[lr * BN + (lc ^ ((lr & (BN / 8 - 1)) << 3))] = f2bf(v);
                }
            }
        }
        __syncthreads();
        constexpr int C8 = BN / 8;
        for (int i = tid; i < BM * C8; i += 256) {
            const int r  = i / C8;
            const int c8 = i % C8;
            const int gc = col0 + c8 * 8;
            if (gc < ncols)
                *(ushortx8*)&((u16*)Cout)[(size_t)(row0 + r) * ldc + gc] =
                    *(const ushortx8*)&cst[r * BN + ((c8 * 8) ^ ((r & (BN / 8 - 1)) << 3))];
        }
    }
}

// ---------------- deep-pipelined GEMM for GEMM1 (T2+T3+T4+T5) ----------------
// 128x256 tile, 8 waves (2Mx4N, 64x64 per wave), BK=64, TRIPLE-buffered LDS
// (144 KiB). Counted s_waitcnt vmcnt(6) at tile boundaries (never 0 in the
// main loop); per K-tile 2 phases of {8 ds_read ; 3 prefetch ; barrier ;
// lgkmcnt(0) ; setprio(1) ; 16 MFMA ; setprio(0) ; barrier}.
__global__ __launch_bounds__(512, 2) void gemm_bf16_dp(
    const u16* __restrict__ A, const u16* __restrict__ Bt, u16* __restrict__ Cout,
    int K, int ldc)
{
    constexpr int BM   = 128;
    constexpr int BN   = 256;
    constexpr int BK   = 64;
    constexpr int SLOT = BK / 8;           // 8 16B slots per row
    constexpr int CR   = 64 / SLOT;        // 8 rows per copy instruction
    constexpr int NACH = BM / CR / 8;      // 2 A copies per wave
    constexpr int NBCH = BN / CR / 8;      // 4 B copies per wave
    constexpr int AST  = BM * BK;          // u16 per A buffer (16 KiB)
    constexpr int BST  = BN * BK;          // u16 per B buffer (32 KiB)

    __shared__ __align__(16) u16 As[3 * AST];
    __shared__ __align__(16) u16 Bs[3 * BST];            // total 144 KiB

    const int tid  = threadIdx.x;
    const int w    = tid >> 6;
    const int lane = tid & 63;
    const int wm   = w & 1;                // 2 waves over M
    const int wn   = w >> 1;               // 4 waves over N
    const int row0 = blockIdx.y * BM;
    const int col0 = blockIdx.x * BN;

    const int srow = lane / SLOT;
    const int kqp  = lane % SLOT;
    const u16* ga[NACH]; int laA[NACH];
    #pragma unroll
    for (int i = 0; i < NACH; ++i) {
        const int c  = w * NACH + i;       // 0..15
        const int r  = c * CR + srow;
        const int kq = kqp ^ ((r >> 1) & (SLOT - 1));
        ga[i]  = A + (size_t)(row0 + r) * K + kq * 8;
        laA[i] = c * CR * BK;
    }
    const u16* gb[NBCH]; int laB[NBCH];
    #pragma unroll
    for (int i = 0; i < NBCH; ++i) {
        const int c  = w * NBCH + i;       // 0..31
        const int r  = c * CR + srow;
        const int kq = kqp ^ ((r >> 1) & (SLOT - 1));
        gb[i]  = Bt + (size_t)(col0 + r) * K + kq * 8;
        laB[i] = c * CR * BK;
    }

    const int q = lane >> 4, l15 = lane & 15;
    int a_off[4][2], b_off[4][2];
    #pragma unroll
    for (int mt = 0; mt < 4; ++mt) {
        const int r = wm * 64 + mt * 16 + l15;
        const int m = (r >> 1) & (SLOT - 1);
        #pragma unroll
        for (int kk = 0; kk < 2; ++kk)
            a_off[mt][kk] = r * BK + ((kk * 4 + q) ^ m) * 8;
    }
    #pragma unroll
    for (int nt = 0; nt < 4; ++nt) {
        const int r = wn * 64 + nt * 16 + l15;
        const int m = (r >> 1) & (SLOT - 1);
        #pragma unroll
        for (int kk = 0; kk < 2; ++kk)
            b_off[nt][kk] = r * BK + ((kk * 4 + q) ^ m) * 8;
    }

    floatx4 acc[4][4];
    #pragma unroll
    for (int mt = 0; mt < 4; ++mt)
        #pragma unroll
        for (int nt = 0; nt < 4; ++nt)
            acc[mt][nt] = (floatx4){0.f, 0.f, 0.f, 0.f};

    const int NTILES = K / BK;             // >= 2 required (GEMM1: 16)

    // prologue: stage K-tiles 0 and 1 into bufs 0,1 (6 loads/wave each)
    #pragma unroll
    for (int i = 0; i < NACH; ++i) { async_copy16(ga[i], &As[0 * AST + laA[i]]); ga[i] += BK; }
    #pragma unroll
    for (int i = 0; i < NBCH; ++i) { async_copy16(gb[i], &Bs[0 * BST + laB[i]]); gb[i] += BK; }
    #pragma unroll
    for (int i = 0; i < NACH; ++i) { async_copy16(ga[i], &As[1 * AST + laA[i]]); ga[i] += BK; }
    #pragma unroll
    for (int i = 0; i < NBCH; ++i) { async_copy16(gb[i], &Bs[1 * BST + laB[i]]); gb[i] += BK; }
    __builtin_amdgcn_sched_barrier(0);
    asm volatile("s_waitcnt vmcnt(6)" ::: "memory");   // tile0 landed; tile1 in flight
    __builtin_amdgcn_s_barrier();
    __builtin_amdgcn_sched_barrier(0);

    int cur = 0, nxt = 2;
    for (int t = 0; t < NTILES; ++t) {
        const bool pf = (t + 2 < NTILES);
        const u16* Ac = &As[cur * AST];
        const u16* Bc = &Bs[cur * BST];
        u16* An = &As[nxt * AST];
        u16* Bn = &Bs[nxt * BST];

        bf16x8 af[4], bfv[4];

        // ---------- phase A: kk = 0 ----------
        #pragma unroll
        for (int mt = 0; mt < 4; ++mt) af[mt]  = *(const bf16x8*)&Ac[a_off[mt][0]];
        #pragma unroll
        for (int nt = 0; nt < 4; ++nt) bfv[nt] = *(const bf16x8*)&Bc[b_off[nt][0]];
        if (pf) {
            async_copy16(ga[0], &An[laA[0]]);
            async_copy16(ga[1], &An[laA[1]]);
            async_copy16(gb[0], &Bn[laB[0]]);
        }
        __builtin_amdgcn_sched_barrier(0);
        __builtin_amdgcn_s_barrier();
        asm volatile("s_waitcnt lgkmcnt(0)" ::: "memory");
        __builtin_amdgcn_sched_barrier(0);
        __builtin_amdgcn_s_setprio(1);
        #pragma unroll
        for (int mt = 0; mt < 4; ++mt)
            #pragma unroll
            for (int nt = 0; nt < 4; ++nt)
                acc[mt][nt] = __builtin_amdgcn_mfma_f32_16x16x32_bf16(
                    af[mt], bfv[nt], acc[mt][nt], 0, 0, 0);
        __builtin_amdgcn_s_setprio(0);
        __builtin_amdgcn_sched_barrier(0);
        __builtin_amdgcn_s_barrier();
        __builtin_amdgcn_sched_barrier(0);

        // ---------- phase B: kk = 1 ----------
        #pragma unroll
        for (int mt = 0; mt < 4; ++mt) af[mt]  = *(const bf16x8*)&Ac[a_off[mt][1]];
        #pragma unroll
        for (int nt = 0; nt < 4; ++nt) bfv[nt] = *(const bf16x8*)&Bc[b_off[nt][1]];
        if (pf) {
            async_copy16(gb[1], &Bn[laB[1]]);
            async_copy16(gb[2], &Bn[laB[2]]);
            async_copy16(gb[3], &Bn[laB[3]]);
            #pragma unroll
            for (int i = 0; i < NACH; ++i) ga[i] += BK;
            #pragma unroll
            for (int i = 0; i < NBCH; ++i) gb[i] += BK;
        }
        __builtin_amdgcn_sched_barrier(0);
        __builtin_amdgcn_s_barrier();
        asm volatile("s_waitcnt lgkmcnt(0)" ::: "memory");
        __builtin_amdgcn_sched_barrier(0);
        __builtin_amdgcn_s_setprio(1);
        #pragma unroll
        for (int mt = 0; mt < 4; ++mt)
            #pragma unroll
            for (int nt = 0; nt < 4; ++nt)
                acc[mt][nt] = __builtin_amdgcn_mfma_f32_16x16x32_bf16(
                    af[mt], bfv[nt], acc[mt][nt], 0, 0, 0);
        __builtin_amdgcn_s_setprio(0);
        __builtin_amdgcn_sched_barrier(0);
        // counted boundary wait: oldest 6 (tile t+1) complete, newest 6
        // (tile t+2) stay in flight. Last two tiles: drain.
        if (pf) asm volatile("s_waitcnt vmcnt(6)" ::: "memory");
        else    asm volatile("s_waitcnt vmcnt(0)" ::: "memory");
        __builtin_amdgcn_s_barrier();
        __builtin_amdgcn_sched_barrier(0);

        cur = (cur == 2) ? 0 : cur + 1;
        nxt = (nxt == 2) ? 0 : nxt + 1;
    }

    // epilogue: stage C-tile (128x256 bf16 = 64 KiB) into Bs, copy out ushort8.
    // swizzle: col ^ ((row & 31) << 3) -- 16B-granular, bijective per row.
    u16* cst = Bs;
    #pragma unroll
    for (int mt = 0; mt < 4; ++mt) {
        #pragma unroll
        for (int nt = 0; nt < 4; ++nt) {
            const int lc = wn * 64 + nt * 16 + l15;
            #pragma unroll
            for (int r = 0; r < 4; ++r) {
                const int lr = wm * 64 + mt * 16 + q * 4 + r;
                cst[lr * 256 + (lc ^ ((lr & 31) << 3))] = f2bf(acc[mt][nt][r]);
            }
        }
    }
    __syncthreads();
    for (int i = tid; i < 128 * 32; i += 512) {
        const int r  = i >> 5;
        const int c8 = i & 31;
        *(ushortx8*)&Cout[(size_t)(row0 + r) * ldc + col0 + c8 * 8] =
            *(const ushortx8*)&cst[r * 256 + ((c8 * 8) ^ ((r & 31) << 3))];
    }
}

// reduce GEMM2 split-K partials (z=8, stride 96): dtBC[row][col] = sum_z part[z][row][col];
// also emit dt_un (cols 0..63) as bf16 for GEMM3.
__global__ __launch_bounds__(256) void reduce_dtbc(
    const float* __restrict__ part, float* __restrict__ dtBC, u16* __restrict__ dtun_b)
{
    int idx = blockIdx.x * 256 + threadIdx.x;
    if (idx >= BL * 96) return;
    const int row = idx / 96;
    const int col = idx - row * 96;
    float s = 0.f;
    #pragma unroll
    for (int z = 0; z < 8; ++z)
        s += part[(size_t)z * BL * 96 + idx];
    dtBC[idx] = s;
    if (col < 64) dtun_b[(size_t)row * 64 + col] = f2bf(s);
}

// reduce GEMM4 split-K partials (z=2) -> f32 d_out, float4-wide
__global__ __launch_bounds__(256) void reduce_out(
    const float* __restrict__ part, float* __restrict__ out)
{
    const int idx = blockIdx.x * 256 + threadIdx.x;   // over BL*EE/4
    const float4 a = ((const float4*)part)[idx];
    const float4 b = ((const float4*)part)[idx + BL * EE / 4];
    float4 o;
    o.x = a.x + b.x; o.y = a.y + b.y; o.z = a.z + b.z; o.w = a.w + b.w;
    ((float4*)out)[idx] = o;
}

// ---------------- conv (depthwise K=4, SAME pad_lo=1) + SiLU + gate ----------------
// 4 consecutive tokens per thread, 7-row rolling window in registers:
// reads 7 conv rows + 4 z rows per 4 outputs (vs 16+4 at 1 token/thread whose
// neighbor re-reads cross XCDs and miss L2). Same FMA count, ~0.6x traffic.
__global__ __launch_bounds__(256) void conv_gate(
    const u16* __restrict__ xzb, const float* __restrict__ filt,
    const float* __restrict__ bias, u16* __restrict__ yb)
{
    const int idx = blockIdx.x * 256 + threadIdx.x;   // over (BL/4)*(DIN/8)
    constexpr int ND8 = DIN / 8;                      // 256: one block = one t4 row
    const int t4 = idx / ND8;
    const int d  = (idx - t4 * ND8) * 8;
    const int b  = t4 >> 8;                           // LL/4 = 256 groups per batch
    const int t0 = (t4 & 255) * 4;

    float ff[4][8];
    #pragma unroll
    for (int k = 0; k < 4; ++k)
        #pragma unroll
        for (int j = 0; j < 8; ++j)
            ff[k][j] = filt[(size_t)k * DIN + d + j];

    float acc[4][8];
    #pragma unroll
    for (int tt = 0; tt < 4; ++tt)
        #pragma unroll
        for (int j = 0; j < 8; ++j)
            acc[tt][j] = bias[d + j];

    #pragma unroll
    for (int s = 0; s < 7; ++s) {
        const int ri = t0 - 1 + s;
        if ((unsigned)ri < (unsigned)LL) {
            const ushortx8 xc = *(const ushortx8*)(xzb + (size_t)(b * LL + ri) * (2 * DIN) + d);
            float xf[8];
            #pragma unroll
            for (int j = 0; j < 8; ++j) xf[j] = bf2f(xc[j]);
            #pragma unroll
            for (int tt = 0; tt < 4; ++tt) {
                const int k = s - tt;                 // tap index (compile-time after unroll)
                if (0 <= k && k < 4) {
                    #pragma unroll
                    for (int j = 0; j < 8; ++j)
                        acc[tt][j] = fmaf(xf[j], ff[k][j], acc[tt][j]);
                }
            }
        }
    }
    #pragma unroll
    for (int tt = 0; tt < 4; ++tt) {
        const int t = t0 + tt;
        const ushortx8 z = *(const ushortx8*)(xzb + (size_t)(b * LL + t) * (2 * DIN) + DIN + d);
        ushortx8 o;
        #pragma unroll
        for (int j = 0; j < 8; ++j)
            o[j] = f2bf(acc[tt][j] / (1.f + __expf(-acc[tt][j])) * bf2f(z[j]));
        *(ushortx8*)(yb + (size_t)(b * LL + t) * DIN + d) = o;
    }
}

// ---------------- SSM chunked scan (dt and u in bf16; NCHUNK=32) ----------------
__global__ __launch_bounds__(256) void scan_phase_a(
    const u16* __restrict__ dt, const u16* __restrict__ u,
    const float* __restrict__ dtBC, const float* __restrict__ A2t,
    float* __restrict__ hend, float* __restrict__ sdtbuf)
{
    const int d = blockIdx.x * 256 + threadIdx.x;
    const int c = blockIdx.y;
    const int b = blockIdx.z;

    __shared__ float Bs[CLEN][NST];
    for (int e = threadIdx.x; e < CLEN * NST; e += 256) {
        const int tl = e >> 4, n = e & 15;
        Bs[tl][n] = dtBC[(size_t)(b * LL + c * CLEN + tl) * 96 + 64 + n];
    }
    __syncthreads();

    float A2r[NST];
    #pragma unroll
    for (int n = 0; n < NST; ++n) A2r[n] = A2t[n * DIN + d];

    float h[NST] = {};
    float sdt = 0.f;
    const size_t tbase = (size_t)(b * LL + c * CLEN) * DIN + d;
    for (int tl = 0; tl < CLEN; ++tl) {
        const float dtv = bf2f(dt[tbase + (size_t)tl * DIN]);
        const float uv  = bf2f(u [tbase + (size_t)tl * DIN]);
        sdt += dtv;
        const float cu = dtv * uv;
        #pragma unroll
        for (int n = 0; n < NST; ++n) {
            const float a = __expf(A2r[n] * dtv);
            h[n] = fmaf(a, h[n], cu * Bs[tl][n]);
        }
    }
    const int cb = b * NCHUNK + c;
    #pragma unroll
    for (int n = 0; n < NST; ++n)
        hend[((size_t)cb * NST + n) * DIN + d] = h[n];
    sdtbuf[(size_t)cb * DIN + d] = sdt;
}

__global__ __launch_bounds__(256) void scan_phase_b(
    const float* __restrict__ A2t, const float* __restrict__ sdtbuf,
    float* __restrict__ hcarry)
{
    const int idx = blockIdx.x * 256 + threadIdx.x;  // b*32768 + n*2048 + d
    if (idx >= BB_ * NST * DIN) return;
    const int d = idx & (DIN - 1);
    const int n = (idx >> 11) & 15;
    const int b = idx >> 15;
    const float A2 = A2t[n * DIN + d];
    float h = 0.f;
    for (int c = 0; c < NCHUNK; ++c) {
        const int cb = b * NCHUNK + c;
        const size_t off = ((size_t)cb * NST + n) * DIN + d;
        const float he = hcarry[off];
        const float pa = __expf(A2 * sdtbuf[(size_t)cb * DIN + d]);
        hcarry[off] = h;
        h = fmaf(pa, h, he);
    }
}

__global__ __launch_bounds__(256) void scan_phase_c(
    const u16* __restrict__ dt, const u16* __restrict__ u,
    const float* __restrict__ dtBC, const float* __restrict__ A2t,
    const float* __restrict__ hinit, const float* __restrict__ Dp,
    u16* __restrict__ ysb)
{
    const int d = blockIdx.x * 256 + threadIdx.x;
    const int c = blockIdx.y;
    const int b = blockIdx.z;

    __shared__ float Bs[CLEN][NST];
    __shared__ float Cs[CLEN][NST];
    for (int e = threadIdx.x; e < CLEN * NST; e += 256) {
        const int tl = e >> 4, n = e & 15;
        const size_t base = (size_t)(b * LL + c * CLEN + tl) * 96;
        Bs[tl][n] = dtBC[base + 64 + n];
        Cs[tl][n] = dtBC[base + 80 + n];
    }
    __syncthreads();

    float A2r[NST], h[NST];
    const int cb = b * NCHUNK + c;
    #pragma unroll
    for (int n = 0; n < NST; ++n) {
        A2r[n] = A2t[n * DIN + d];
        h[n]   = hinit[((size_t)cb * NST + n) * DIN + d];
    }
    const float Dv = Dp[d];

    const size_t tbase = (size_t)(b * LL + c * CLEN) * DIN + d;
    for (int tl = 0; tl < CLEN; ++tl) {
        const float dtv = bf2f(dt[tbase + (size_t)tl * DIN]);
        const float uv  = bf2f(u [tbase + (size_t)tl * DIN]);
        const float cu = dtv * uv;
        float yacc = 0.f;
        #pragma unroll
        for (int n = 0; n < NST; ++n) {
            const float a = __expf(A2r[n] * dtv);
            h[n] = fmaf(a, h[n], cu * Bs[tl][n]);
            yacc = fmaf(h[n], Cs[tl][n], yacc);
        }
        ysb[tbase + (size_t)tl * DIN] = f2bf(fmaf(Dv, uv, yacc));
    }
}

// ---------------- launcher ----------------
extern "C" void kernel_launch(void* const* d_in, const int* in_sizes, int n_in,
                              void* d_out, int out_size, void* d_ws, size_t ws_size,
                              hipStream_t stream)
{
    const float* x       = (const float*)d_in[0];
    const float* in_g1   = (const float*)d_in[1];
    const float* in_g2   = (const float*)d_in[2];
    const float* x_g1    = (const float*)d_in[3];
    const float* x_g2    = (const float*)d_in[4];
    const float* dt_g1   = (const float*)d_in[5];
    const float* dt_g2   = (const float*)d_in[6];
    const float* out_g1  = (const float*)d_in[7];
    const float* out_g2  = (const float*)d_in[8];
    const float* filt    = (const float*)d_in[9];
    const float* bias    = (const float*)d_in[10];
    const float* A_log   = (const float*)d_in[11];
    const float* Dp      = (const float*)d_in[12];

    float* ws     = (float*)d_ws;
    u16*   W_inT  = (u16*)(ws + OFF_WINT);
    u16*   W_outT = (u16*)(ws + OFF_WOUTT);
    u16*   W_xT   = (u16*)(ws + OFF_WXT);
    u16*   W_dtT  = (u16*)(ws + OFF_WDTT);
    float* A2t    = ws + OFF_A2T;
    u16*   xb     = (u16*)(ws + OFF_XB);
    u16*   xzb    = (u16*)(ws + OFF_XZB);
    u16*   yb     = (u16*)(ws + OFF_YB);
    float* part   = ws + OFF_PART;
    float* dtBC   = ws + OFF_DTBC;
    u16*   dtun_b = (u16*)(ws + OFF_DTUNB);
    u16*   dtb    = (u16*)(ws + OFF_DTB);
    u16*   ysb    = (u16*)(ws + OFF_YSB);
    float* hc     = ws + OFF_HC;
    float* sdt    = ws + OFF_SDT;

    // 1) all prep in one launch: W_inT, W_outT, W_xT, W_dtT, x->bf16, A2t
    mega_prep<<<4800, 256, 0, stream>>>(
        in_g1, in_g2, W_inT, out_g1, out_g2, W_outT,
        x_g1, x_g2, W_xT, dt_g1, dt_g2, W_dtT,
        x, xb, A_log, A2t);

    // 2) xz = x @ W_in  (M=2048, N=4096, K=1024) -> bf16 (deep-pipelined)
    gemm_bf16_dp<<<dim3(16, 16, 1), 512, 0, stream>>>(
        xb, W_inT, xzb, EE, 4096);

    // 3) y = silu(conv(xc) + bias) * z  -> bf16, 4 tokens/thread rolling window
    conv_gate<<<(BL / 4) * (DIN / 8) / 256, 256, 0, stream>>>(xzb, filt, bias, yb);

    // 4) dtBC partials = y @ W_x (M=2048, N=128->96, K=2048), split-K z=8, BN=64
    gemm_bf16<64, 64, 0><<<dim3(2, 16, 8), 256, 0, stream>>>(
        yb, W_xT, part, DIN, 96, 256, (size_t)BL * 96, 96);
    reduce_dtbc<<<(BL * 96 + 255) / 256, 256, 0, stream>>>(part, dtBC, dtun_b);

    // 5) dt = softplus(dt_un @ W_dt) (M=2048, N=2048, K=64) -> bf16
    gemm_bf16<64, 64, 2><<<dim3(32, 16, 1), 256, 0, stream>>>(
        dtun_b, W_dtT, dtb, 64, DIN, 64, 0, DIN);

    // 6) SSM chunked scan, NCHUNK=32 (512 blocks = 2/CU)
    scan_phase_a<<<dim3(DIN / 256, NCHUNK, BB_), 256, 0, stream>>>(dtb, yb, dtBC, A2t, hc, sdt);
    scan_phase_b<<<(BB_ * NST * DIN) / 256, 256, 0, stream>>>(A2t, sdt, hc);
    scan_phase_c<<<dim3(DIN / 256, NCHUNK, BB_), 256, 0, stream>>>(dtb, yb, dtBC, A2t, hc, Dp, ysb);

    // 7) out = ssm @ W_out (M=2048, N=1024, K=2048), split-K z=2 (512 blocks = 2/CU)
    //    [proven: split-K + reduce beats both 1-block/CU direct (R3: +8µs) and
    //     2-way-colliding atomicAdd (R5: +4µs)]
    gemm_bf16<64, 64, 0><<<dim3(16, 16, 2), 256, 0, stream>>>(
        ysb, W_outT, part, DIN, EE, EE, (size_t)BL * EE, EE);
    reduce_out<<<(BL * EE / 4) / 256, 256, 0, stream>>>(part, (float*)d_out);
}

// Round 7
// 220.964 us; speedup vs baseline: 1.0208x; 1.0027x over previous
//
#include <hip/hip_runtime.h>
#include <hip/hip_bf16.h>
#include <cstdint>
#include <cstddef>

// Problem constants
#define EE    1024
#define DIN   2048
#define NST   16
#define DTR   64
#define BB_   2
#define LL    1024
#define BL    (BB_*LL)        // 2048 tokens
#define NCHUNK 32
#define CLEN   32             // 1024 / 32
#define RTT   16              // TT rank (all four factor pairs)

typedef unsigned short u16;
typedef unsigned int   u32;

// ---------------- workspace layout (in floats) ----------------
static constexpr size_t OFF_WINT  = 0;                   // bf16 [4096][1024]
static constexpr size_t OFF_WOUTT = 2097152;             // bf16 [1024][2048]
static constexpr size_t OFF_WXT   = 3145728;             // bf16 [128][2048] rows>=96 zero
static constexpr size_t OFF_WDTT  = 3276800;             // bf16 [2048][64]
static constexpr size_t OFF_A2T   = 3342336;             // f32  [16][2048]
static constexpr size_t OFF_XB    = 3375104;             // bf16 [2048][1024]
static constexpr size_t OFF_XZB   = 4423680;             // bf16 [2048][4096]
static constexpr size_t OFF_YB    = 8617984;             // bf16 [2048][2048]
static constexpr size_t OFF_PART  = 10715136;            // f32  GEMM2 partials [8][2048][96]
static constexpr size_t OFF_DTBC  = 14909440;            // f32  [2048][96]
static constexpr size_t OFF_DTUNB = 15106048;            // bf16 [2048][64]
static constexpr size_t OFF_DTB   = 15171584;            // bf16 [2048][2048] (dt)
static constexpr size_t OFF_YSB   = 17268736;            // bf16 [2048][2048]
static constexpr size_t OFF_HC    = 19365888;            // f32  [2*32][16][2048] carries
static constexpr size_t OFF_SDT   = 21463040;            // f32  [2*32][2048]
static constexpr size_t OFF_PART4 = 25165824;            // f32  GEMM4 partials [4][2048][1024] (33.5 MB @ +96 MiB)

// ---------------- helpers ----------------
__device__ __forceinline__ u16 f2bf(float f) {   // RNE f32->bf16
    u32 u = __float_as_uint(f);
    u += 0x7fffu + ((u >> 16) & 1u);
    return (u16)(u >> 16);
}
__device__ __forceinline__ float bf2f(u16 v) {
    return __uint_as_float((u32)v << 16);
}

__device__ __forceinline__ void async_copy16(const void* g, void* l) {
    __builtin_amdgcn_global_load_lds((const __attribute__((address_space(1))) u32*)g,
                                     (__attribute__((address_space(3))) u32*)l,
                                     16, 0, 0);
}

__device__ __forceinline__ float softplusf(float v) {
    return fmaxf(v, 0.f) + log1pf(__expf(-fabsf(v)));
}

// ---------------- fused prep: 4 TT builds + x->bf16 + A2t ----------------
// 2 columns per block (halves block count: gather-latency-bound, not FLOP-bound)
__device__ void tt_part(const float* __restrict__ g1, const float* __restrict__ g2,
                        u16* __restrict__ Wt, int m1, int n1, int m2, int n2,
                        int c, int crows, float* g1col, float* g2col)
{
    const int rowsW = m1 * m2;
    if (c >= crows) {                      // zero padding rows (GEMM2 N-pad)
        for (int k = threadIdx.x; k < rowsW; k += 256)
            Wt[(size_t)c * rowsW + k] = 0;
        return;
    }
    __syncthreads();                       // protect smem from previous call's readers
    const int i = c / n2;
    const int j = c - i * n2;

    for (int e = threadIdx.x; e < m1 * RTT; e += 256) {
        const int a = e >> 4, rr = e & 15;
        g1col[e] = g1[(size_t)(a * n1 + i) * RTT + rr];
    }
    for (int e = threadIdx.x; e < RTT * m2; e += 256) {
        const int rr = e / m2, bb = e - rr * m2;
        g2col[e] = g2[(size_t)(rr * m2 + bb) * n2 + j];
    }
    __syncthreads();

    for (int k = threadIdx.x; k < rowsW; k += 256) {
        const int a  = k / m2;
        const int bb = k - a * m2;
        const float* gp = g1col + a * RTT;
        float s = 0.f;
        #pragma unroll
        for (int rr = 0; rr < RTT; ++rr)
            s = fmaf(gp[rr], g2col[rr * m2 + bb], s);
        Wt[(size_t)c * rowsW + k] = f2bf(s);
    }
}

__global__ __launch_bounds__(256) void mega_prep(
    const float* __restrict__ in_g1, const float* __restrict__ in_g2, u16* __restrict__ W_inT,
    const float* __restrict__ out_g1, const float* __restrict__ out_g2, u16* __restrict__ W_outT,
    const float* __restrict__ x_g1, const float* __restrict__ x_g2, u16* __restrict__ W_xT,
    const float* __restrict__ dt_g1, const float* __restrict__ dt_g2, u16* __restrict__ W_dtT,
    const float* __restrict__ x, u16* __restrict__ xb,
    const float* __restrict__ A_log, float* __restrict__ A2t)
{
    __shared__ float g1col[32 * RTT];
    __shared__ float g2col[RTT * 64];
    const int blk = blockIdx.x;
    if (blk < 2048) {                                      // W_inT: 4096 cols
        const int c = blk * 2;
        tt_part(in_g1, in_g2, W_inT, 32, 64, 32, 64, c,     4096, g1col, g2col);
        tt_part(in_g1, in_g2, W_inT, 32, 64, 32, 64, c + 1, 4096, g1col, g2col);
    } else if (blk < 2560) {                               // W_outT: 1024 cols
        const int c = (blk - 2048) * 2;
        tt_part(out_g1, out_g2, W_outT, 32, 32, 64, 32, c,     1024, g1col, g2col);
        tt_part(out_g1, out_g2, W_outT, 32, 32, 64, 32, c + 1, 1024, g1col, g2col);
    } else if (blk < 2624) {                               // W_xT: 128 cols (96 real)
        const int c = (blk - 2560) * 2;
        tt_part(x_g1, x_g2, W_xT, 32, 8, 64, 12, c,     96, g1col, g2col);
        tt_part(x_g1, x_g2, W_xT, 32, 8, 64, 12, c + 1, 96, g1col, g2col);
    } else if (blk < 3648) {                               // W_dtT: 2048 cols
        const int c = (blk - 2624) * 2;
        tt_part(dt_g1, dt_g2, W_dtT, 8, 32, 8, 64, c,     2048, g1col, g2col);
        tt_part(dt_g1, dt_g2, W_dtT, 8, 32, 8, 64, c + 1, 2048, g1col, g2col);
    } else if (blk < 4672) {                               // x -> bf16 (2 float4/thread)
        const int i0 = (blk - 3648) * 512 + threadIdx.x;
        #pragma unroll
        for (int s = 0; s < 2; ++s) {
            const int i = i0 + s * 256;
            float4 v = ((const float4*)x)[i];
            ushort4 o;
            o.x = f2bf(v.x); o.y = f2bf(v.y); o.z = f2bf(v.z); o.w = f2bf(v.w);
            ((ushort4*)xb)[i] = o;
        }
    } else {                                               // A2t (128 blocks)
        const int idx = (blk - 4672) * 256 + threadIdx.x;  // over DIN*NST
        const int d = idx >> 4, n = idx & 15;
        A2t[n * DIN + d] = -expf(A_log[idx]);
    }
}

// ---------------- bf16 MFMA GEMM (templated BN / BK / output mode) ----------------
// C = A[M,K] @ Bt[N,K]^T. A/Bt row-major bf16 (row stride K). BM=128.
// XOR swizzle on 16B k-slots: LDS pos s holds global slot s^((r>>1)&(SLOT-1)).
// Split-K: blockIdx.z picks K-chunk + output plane (czstride).
// OUT: 0 = f32 store (ncols-guarded), 1 = bf16, 2 = softplus+bf16.
// bf16 outputs (OUT 1/2) staged through LDS -> coalesced ushort8 stores.
typedef __attribute__((ext_vector_type(8))) short bf16x8;
typedef __attribute__((ext_vector_type(4))) float floatx4;
typedef __attribute__((ext_vector_type(8))) unsigned short ushortx8;

template<int BN, int BK, int OUT>
__global__ __launch_bounds__(256) void gemm_bf16(
    const u16* __restrict__ A, const u16* __restrict__ Bt, void* __restrict__ Cout,
    int K, int ldc, int kchunk, size_t czstride, int ncols)
{
    constexpr int BM   = 128;
    constexpr int NT   = BN / 32;          // n-tiles per wave
    constexpr int SLOT = BK / 8;           // 16B slots per LDS row
    constexpr int CR   = 64 / SLOT;        // rows per copy instruction
    constexpr int NACH = BM / CR / 4;      // A copies per wave
    constexpr int NBCH = BN / CR / 4;      // B copies per wave
    constexpr int KG   = BK / 32;          // MFMA k-groups per step
    __shared__ __align__(16) u16 smem[BM * BK + BN * BK];
    u16* As = smem;
    u16* Bs = smem + BM * BK;

    const int tid  = threadIdx.x;
    const int w    = tid >> 6;
    const int lane = tid & 63;
    const int wm   = w & 1, wn = w >> 1;
    const int row0 = blockIdx.y * BM;
    const int col0 = blockIdx.x * BN;
    const int kbeg = blockIdx.z * kchunk;

    const int srow = lane / SLOT;
    const int kqp  = lane % SLOT;
    const u16* ga[NACH]; u16* la[NACH];
    #pragma unroll
    for (int i = 0; i < NACH; ++i) {
        const int c  = w * NACH + i;
        const int r  = c * CR + srow;
        const int kq = kqp ^ ((r >> 1) & (SLOT - 1));
        ga[i] = A + (size_t)(row0 + r) * K + kbeg + kq * 8;
        la[i] = &As[c * CR * BK];
    }
    const u16* gb[NBCH]; u16* lb[NBCH];
    #pragma unroll
    for (int i = 0; i < NBCH; ++i) {
        const int c  = w * NBCH + i;
        const int r  = c * CR + srow;
        const int kq = kqp ^ ((r >> 1) & (SLOT - 1));
        gb[i] = Bt + (size_t)(col0 + r) * K + kbeg + kq * 8;
        lb[i] = &Bs[c * CR * BK];
    }

    const int q = lane >> 4, l15 = lane & 15;
    int a_off[4][KG], b_off[NT][KG];
    #pragma unroll
    for (int mt = 0; mt < 4; ++mt) {
        const int r = wm * 64 + mt * 16 + l15;
        const int m = (r >> 1) & (SLOT - 1);
        #pragma unroll
        for (int kk = 0; kk < KG; ++kk)
            a_off[mt][kk] = r * BK + ((kk * 4 + q) ^ m) * 8;
    }
    #pragma unroll
    for (int nt = 0; nt < NT; ++nt) {
        const int r = wn * (BN / 2) + nt * 16 + l15;
        const int m = (r >> 1) & (SLOT - 1);
        #pragma unroll
        for (int kk = 0; kk < KG; ++kk)
            b_off[nt][kk] = r * BK + ((kk * 4 + q) ^ m) * 8;
    }

    floatx4 acc[4][NT];
    #pragma unroll
    for (int mt = 0; mt < 4; ++mt)
        #pragma unroll
        for (int nt = 0; nt < NT; ++nt)
            acc[mt][nt] = (floatx4){0.f, 0.f, 0.f, 0.f};

    for (int k0 = 0; k0 < kchunk; k0 += BK) {
        #pragma unroll
        for (int i = 0; i < NACH; ++i) { async_copy16(ga[i], la[i]); ga[i] += BK; }
        #pragma unroll
        for (int i = 0; i < NBCH; ++i) { async_copy16(gb[i], lb[i]); gb[i] += BK; }
        __syncthreads();   // drains vmcnt -> tiles ready

        bf16x8 af[4][KG], bfv[NT][KG];
        #pragma unroll
        for (int mt = 0; mt < 4; ++mt)
            #pragma unroll
            for (int kk = 0; kk < KG; ++kk)
                af[mt][kk] = *(const bf16x8*)&As[a_off[mt][kk]];
        #pragma unroll
        for (int nt = 0; nt < NT; ++nt)
            #pragma unroll
            for (int kk = 0; kk < KG; ++kk)
                bfv[nt][kk] = *(const bf16x8*)&Bs[b_off[nt][kk]];

        #pragma unroll
        for (int kk = 0; kk < KG; ++kk)
            #pragma unroll
            for (int mt = 0; mt < 4; ++mt)
                #pragma unroll
                for (int nt = 0; nt < NT; ++nt)
                    acc[mt][nt] = __builtin_amdgcn_mfma_f32_16x16x32_bf16(
                        af[mt][kk], bfv[nt][kk], acc[mt][nt], 0, 0, 0);

        __syncthreads();   // reads done before next stage overwrites
    }

    // epilogue: C/D layout col=lane&15, row=(lane>>4)*4+reg  [verified m89/m91]
    if constexpr (OUT == 0) {
        #pragma unroll
        for (int mt = 0; mt < 4; ++mt) {
            const int row = row0 + wm * 64 + mt * 16 + q * 4;
            #pragma unroll
            for (int nt = 0; nt < NT; ++nt) {
                const int col = col0 + wn * (BN / 2) + nt * 16 + l15;
                if (col < ncols) {
                    #pragma unroll
                    for (int r = 0; r < 4; ++r)
                        ((float*)Cout)[(size_t)blockIdx.z * czstride + (size_t)(row + r) * ldc + col] = acc[mt][nt][r];
                }
            }
        }
    } else {
        // stage to LDS with a 16B-granular XOR swizzle, then coalesced copy-out
        u16* cst = smem;                                 // BM*BN u16 fits (BN<=128)
        #pragma unroll
        for (int mt = 0; mt < 4; ++mt) {
            #pragma unroll
            for (int nt = 0; nt < NT; ++nt) {
                const int lc = wn * (BN / 2) + nt * 16 + l15;
                #pragma unroll
                for (int r = 0; r < 4; ++r) {
                    float v = acc[mt][nt][r];
                    if constexpr (OUT == 2) v = softplusf(v);
                    const int lr = wm * 64 + mt * 16 + q * 4 + r;
                    cst[lr * BN + (lc ^ ((lr & (BN / 8 - 1)) << 3))] = f2bf(v);
                }
            }
        }
        __syncthreads();
        constexpr int C8 = BN / 8;
        for (int i = tid; i < BM * C8; i += 256) {
            const int r  = i / C8;
            const int c8 = i % C8;
            const int gc = col0 + c8 * 8;
            if (gc < ncols)
                *(ushortx8*)&((u16*)Cout)[(size_t)(row0 + r) * ldc + gc] =
                    *(const ushortx8*)&cst[r * BN + ((c8 * 8) ^ ((r & (BN / 8 - 1)) << 3))];
        }
    }
}

// ---------------- deep-pipelined GEMM for GEMM1 (T2+T3+T4+T5) ----------------
// 128x256 tile, 8 waves (2Mx4N, 64x64 per wave), BK=64, TRIPLE-buffered LDS
// (144 KiB). Counted s_waitcnt vmcnt(6) at tile boundaries (never 0 in the
// main loop); per K-tile 2 phases of {8 ds_read ; 3 prefetch ; barrier ;
// lgkmcnt(0) ; setprio(1) ; 16 MFMA ; setprio(0) ; barrier}.
__global__ __launch_bounds__(512, 2) void gemm_bf16_dp(
    const u16* __restrict__ A, const u16* __restrict__ Bt, u16* __restrict__ Cout,
    int K, int ldc)
{
    constexpr int BM   = 128;
    constexpr int BN   = 256;
    constexpr int BK   = 64;
    constexpr int SLOT = BK / 8;           // 8 16B slots per row
    constexpr int CR   = 64 / SLOT;        // 8 rows per copy instruction
    constexpr int NACH = BM / CR / 8;      // 2 A copies per wave
    constexpr int NBCH = BN / CR / 8;      // 4 B copies per wave
    constexpr int AST  = BM * BK;          // u16 per A buffer (16 KiB)
    constexpr int BST  = BN * BK;          // u16 per B buffer (32 KiB)

    __shared__ __align__(16) u16 As[3 * AST];
    __shared__ __align__(16) u16 Bs[3 * BST];            // total 144 KiB

    const int tid  = threadIdx.x;
    const int w    = tid >> 6;
    const int lane = tid & 63;
    const int wm   = w & 1;                // 2 waves over M
    const int wn   = w >> 1;               // 4 waves over N
    const int row0 = blockIdx.y * BM;
    const int col0 = blockIdx.x * BN;

    const int srow = lane / SLOT;
    const int kqp  = lane % SLOT;
    const u16* ga[NACH]; int laA[NACH];
    #pragma unroll
    for (int i = 0; i < NACH; ++i) {
        const int c  = w * NACH + i;       // 0..15
        const int r  = c * CR + srow;
        const int kq = kqp ^ ((r >> 1) & (SLOT - 1));
        ga[i]  = A + (size_t)(row0 + r) * K + kq * 8;
        laA[i] = c * CR * BK;
    }
    const u16* gb[NBCH]; int laB[NBCH];
    #pragma unroll
    for (int i = 0; i < NBCH; ++i) {
        const int c  = w * NBCH + i;       // 0..31
        const int r  = c * CR + srow;
        const int kq = kqp ^ ((r >> 1) & (SLOT - 1));
        gb[i]  = Bt + (size_t)(col0 + r) * K + kq * 8;
        laB[i] = c * CR * BK;
    }

    const int q = lane >> 4, l15 = lane & 15;
    int a_off[4][2], b_off[4][2];
    #pragma unroll
    for (int mt = 0; mt < 4; ++mt) {
        const int r = wm * 64 + mt * 16 + l15;
        const int m = (r >> 1) & (SLOT - 1);
        #pragma unroll
        for (int kk = 0; kk < 2; ++kk)
            a_off[mt][kk] = r * BK + ((kk * 4 + q) ^ m) * 8;
    }
    #pragma unroll
    for (int nt = 0; nt < 4; ++nt) {
        const int r = wn * 64 + nt * 16 + l15;
        const int m = (r >> 1) & (SLOT - 1);
        #pragma unroll
        for (int kk = 0; kk < 2; ++kk)
            b_off[nt][kk] = r * BK + ((kk * 4 + q) ^ m) * 8;
    }

    floatx4 acc[4][4];
    #pragma unroll
    for (int mt = 0; mt < 4; ++mt)
        #pragma unroll
        for (int nt = 0; nt < 4; ++nt)
            acc[mt][nt] = (floatx4){0.f, 0.f, 0.f, 0.f};

    const int NTILES = K / BK;             // >= 2 required (GEMM1: 16)

    // prologue: stage K-tiles 0 and 1 into bufs 0,1 (6 loads/wave each)
    #pragma unroll
    for (int i = 0; i < NACH; ++i) { async_copy16(ga[i], &As[0 * AST + laA[i]]); ga[i] += BK; }
    #pragma unroll
    for (int i = 0; i < NBCH; ++i) { async_copy16(gb[i], &Bs[0 * BST + laB[i]]); gb[i] += BK; }
    #pragma unroll
    for (int i = 0; i < NACH; ++i) { async_copy16(ga[i], &As[1 * AST + laA[i]]); ga[i] += BK; }
    #pragma unroll
    for (int i = 0; i < NBCH; ++i) { async_copy16(gb[i], &Bs[1 * BST + laB[i]]); gb[i] += BK; }
    __builtin_amdgcn_sched_barrier(0);
    asm volatile("s_waitcnt vmcnt(6)" ::: "memory");   // tile0 landed; tile1 in flight
    __builtin_amdgcn_s_barrier();
    __builtin_amdgcn_sched_barrier(0);

    int cur = 0, nxt = 2;
    for (int t = 0; t < NTILES; ++t) {
        const bool pf = (t + 2 < NTILES);
        const u16* Ac = &As[cur * AST];
        const u16* Bc = &Bs[cur * BST];
        u16* An = &As[nxt * AST];
        u16* Bn = &Bs[nxt * BST];

        bf16x8 af[4], bfv[4];

        // ---------- phase A: kk = 0 ----------
        #pragma unroll
        for (int mt = 0; mt < 4; ++mt) af[mt]  = *(const bf16x8*)&Ac[a_off[mt][0]];
        #pragma unroll
        for (int nt = 0; nt < 4; ++nt) bfv[nt] = *(const bf16x8*)&Bc[b_off[nt][0]];
        if (pf) {
            async_copy16(ga[0], &An[laA[0]]);
            async_copy16(ga[1], &An[laA[1]]);
            async_copy16(gb[0], &Bn[laB[0]]);
        }
        __builtin_amdgcn_sched_barrier(0);
        __builtin_amdgcn_s_barrier();
        asm volatile("s_waitcnt lgkmcnt(0)" ::: "memory");
        __builtin_amdgcn_sched_barrier(0);
        __builtin_amdgcn_s_setprio(1);
        #pragma unroll
        for (int mt = 0; mt < 4; ++mt)
            #pragma unroll
            for (int nt = 0; nt < 4; ++nt)
                acc[mt][nt] = __builtin_amdgcn_mfma_f32_16x16x32_bf16(
                    af[mt], bfv[nt], acc[mt][nt], 0, 0, 0);
        __builtin_amdgcn_s_setprio(0);
        __builtin_amdgcn_sched_barrier(0);
        __builtin_amdgcn_s_barrier();
        __builtin_amdgcn_sched_barrier(0);

        // ---------- phase B: kk = 1 ----------
        #pragma unroll
        for (int mt = 0; mt < 4; ++mt) af[mt]  = *(const bf16x8*)&Ac[a_off[mt][1]];
        #pragma unroll
        for (int nt = 0; nt < 4; ++nt) bfv[nt] = *(const bf16x8*)&Bc[b_off[nt][1]];
        if (pf) {
            async_copy16(gb[1], &Bn[laB[1]]);
            async_copy16(gb[2], &Bn[laB[2]]);
            async_copy16(gb[3], &Bn[laB[3]]);
            #pragma unroll
            for (int i = 0; i < NACH; ++i) ga[i] += BK;
            #pragma unroll
            for (int i = 0; i < NBCH; ++i) gb[i] += BK;
        }
        __builtin_amdgcn_sched_barrier(0);
        __builtin_amdgcn_s_barrier();
        asm volatile("s_waitcnt lgkmcnt(0)" ::: "memory");
        __builtin_amdgcn_sched_barrier(0);
        __builtin_amdgcn_s_setprio(1);
        #pragma unroll
        for (int mt = 0; mt < 4; ++mt)
            #pragma unroll
            for (int nt = 0; nt < 4; ++nt)
                acc[mt][nt] = __builtin_amdgcn_mfma_f32_16x16x32_bf16(
                    af[mt], bfv[nt], acc[mt][nt], 0, 0, 0);
        __builtin_amdgcn_s_setprio(0);
        __builtin_amdgcn_sched_barrier(0);
        // counted boundary wait: oldest 6 (tile t+1) complete, newest 6
        // (tile t+2) stay in flight. Last two tiles: drain.
        if (pf) asm volatile("s_waitcnt vmcnt(6)" ::: "memory");
        else    asm volatile("s_waitcnt vmcnt(0)" ::: "memory");
        __builtin_amdgcn_s_barrier();
        __builtin_amdgcn_sched_barrier(0);

        cur = (cur == 2) ? 0 : cur + 1;
        nxt = (nxt == 2) ? 0 : nxt + 1;
    }

    // epilogue: stage C-tile (128x256 bf16 = 64 KiB) into Bs, copy out ushort8.
    // swizzle: col ^ ((row & 31) << 3) -- 16B-granular, bijective per row.
    u16* cst = Bs;
    #pragma unroll
    for (int mt = 0; mt < 4; ++mt) {
        #pragma unroll
        for (int nt = 0; nt < 4; ++nt) {
            const int lc = wn * 64 + nt * 16 + l15;
            #pragma unroll
            for (int r = 0; r < 4; ++r) {
                const int lr = wm * 64 + mt * 16 + q * 4 + r;
                cst[lr * 256 + (lc ^ ((lr & 31) << 3))] = f2bf(acc[mt][nt][r]);
            }
        }
    }
    __syncthreads();
    for (int i = tid; i < 128 * 32; i += 512) {
        const int r  = i >> 5;
        const int c8 = i & 31;
        *(ushortx8*)&Cout[(size_t)(row0 + r) * ldc + col0 + c8 * 8] =
            *(const ushortx8*)&cst[r * 256 + ((c8 * 8) ^ ((r & 31) << 3))];
    }
}

// reduce GEMM2 split-K partials (z=8, stride 96): dtBC[row][col] = sum_z part[z][row][col];
// also emit dt_un (cols 0..63) as bf16 for GEMM3.
__global__ __launch_bounds__(256) void reduce_dtbc(
    const float* __restrict__ part, float* __restrict__ dtBC, u16* __restrict__ dtun_b)
{
    int idx = blockIdx.x * 256 + threadIdx.x;
    if (idx >= BL * 96) return;
    const int row = idx / 96;
    const int col = idx - row * 96;
    float s = 0.f;
    #pragma unroll
    for (int z = 0; z < 8; ++z)
        s += part[(size_t)z * BL * 96 + idx];
    dtBC[idx] = s;
    if (col < 64) dtun_b[(size_t)row * 64 + col] = f2bf(s);
}

// reduce GEMM4 split-K partials (z=4) -> f32 d_out, float4-wide
__global__ __launch_bounds__(256) void reduce_out(
    const float* __restrict__ part, float* __restrict__ out)
{
    const int idx = blockIdx.x * 256 + threadIdx.x;   // over BL*EE/4
    const float4 a = ((const float4*)part)[idx];
    const float4 b = ((const float4*)part)[idx + BL * EE / 4];
    const float4 c = ((const float4*)part)[idx + 2 * (BL * EE / 4)];
    const float4 d = ((const float4*)part)[idx + 3 * (BL * EE / 4)];
    float4 o;
    o.x = (a.x + b.x) + (c.x + d.x);
    o.y = (a.y + b.y) + (c.y + d.y);
    o.z = (a.z + b.z) + (c.z + d.z);
    o.w = (a.w + b.w) + (c.w + d.w);
    ((float4*)out)[idx] = o;
}

// ---------------- conv (depthwise K=4, SAME pad_lo=1) + SiLU + gate ----------------
// 2 consecutive tokens per thread, 5-row rolling window in registers:
// reads 5 conv rows + 2 z rows per 2 outputs. Middle ground between 1-tok
// (5 rows/out, 8 blk/CU) and 4-tok (2.75 rows/out, 2 blk/CU): 3.5 rows/out
// at 4 blk/CU -- R6 showed the traffic/TLP optimum lies between.
__global__ __launch_bounds__(256) void conv_gate(
    const u16* __restrict__ xzb, const float* __restrict__ filt,
    const float* __restrict__ bias, u16* __restrict__ yb)
{
    const int idx = blockIdx.x * 256 + threadIdx.x;   // over (BL/2)*(DIN/8)
    constexpr int ND8 = DIN / 8;                      // 256
    const int t2 = idx / ND8;
    const int d  = (idx - t2 * ND8) * 8;
    const int b  = t2 >> 9;                           // LL/2 = 512 groups per batch
    const int t0 = (t2 & 511) * 2;

    float ff[4][8];
    #pragma unroll
    for (int k = 0; k < 4; ++k)
        #pragma unroll
        for (int j = 0; j < 8; ++j)
            ff[k][j] = filt[(size_t)k * DIN + d + j];

    float acc[2][8];
    #pragma unroll
    for (int tt = 0; tt < 2; ++tt)
        #pragma unroll
        for (int j = 0; j < 8; ++j)
            acc[tt][j] = bias[d + j];

    #pragma unroll
    for (int s = 0; s < 5; ++s) {
        const int ri = t0 - 1 + s;
        if ((unsigned)ri < (unsigned)LL) {
            const ushortx8 xc = *(const ushortx8*)(xzb + (size_t)(b * LL + ri) * (2 * DIN) + d);
            float xf[8];
            #pragma unroll
            for (int j = 0; j < 8; ++j) xf[j] = bf2f(xc[j]);
            #pragma unroll
            for (int tt = 0; tt < 2; ++tt) {
                const int k = s - tt;                 // tap index (compile-time after unroll)
                if (0 <= k && k < 4) {
                    #pragma unroll
                    for (int j = 0; j < 8; ++j)
                        acc[tt][j] = fmaf(xf[j], ff[k][j], acc[tt][j]);
                }
            }
        }
    }
    #pragma unroll
    for (int tt = 0; tt < 2; ++tt) {
        const int t = t0 + tt;
        const ushortx8 z = *(const ushortx8*)(xzb + (size_t)(b * LL + t) * (2 * DIN) + DIN + d);
        ushortx8 o;
        #pragma unroll
        for (int j = 0; j < 8; ++j)
            o[j] = f2bf(acc[tt][j] / (1.f + __expf(-acc[tt][j])) * bf2f(z[j]));
        *(ushortx8*)(yb + (size_t)(b * LL + t) * DIN + d) = o;
    }
}

// ---------------- SSM chunked scan (dt and u in bf16; NCHUNK=32) ----------------
__global__ __launch_bounds__(256) void scan_phase_a(
    const u16* __restrict__ dt, const u16* __restrict__ u,
    const float* __restrict__ dtBC, const float* __restrict__ A2t,
    float* __restrict__ hend, float* __restrict__ sdtbuf)
{
    const int d = blockIdx.x * 256 + threadIdx.x;
    const int c = blockIdx.y;
    const int b = blockIdx.z;

    __shared__ float Bs[CLEN][NST];
    for (int e = threadIdx.x; e < CLEN * NST; e += 256) {
        const int tl = e >> 4, n = e & 15;
        Bs[tl][n] = dtBC[(size_t)(b * LL + c * CLEN + tl) * 96 + 64 + n];
    }
    __syncthreads();

    float A2r[NST];
    #pragma unroll
    for (int n = 0; n < NST; ++n) A2r[n] = A2t[n * DIN + d];

    float h[NST] = {};
    float sdt = 0.f;
    const size_t tbase = (size_t)(b * LL + c * CLEN) * DIN + d;
    for (int tl = 0; tl < CLEN; ++tl) {
        const float dtv = bf2f(dt[tbase + (size_t)tl * DIN]);
        const float uv  = bf2f(u [tbase + (size_t)tl * DIN]);
        sdt += dtv;
        const float cu = dtv * uv;
        #pragma unroll
        for (int n = 0; n < NST; ++n) {
            const float a = __expf(A2r[n] * dtv);
            h[n] = fmaf(a, h[n], cu * Bs[tl][n]);
        }
    }
    const int cb = b * NCHUNK + c;
    #pragma unroll
    for (int n = 0; n < NST; ++n)
        hend[((size_t)cb * NST + n) * DIN + d] = h[n];
    sdtbuf[(size_t)cb * DIN + d] = sdt;
}

__global__ __launch_bounds__(256) void scan_phase_b(
    const float* __restrict__ A2t, const float* __restrict__ sdtbuf,
    float* __restrict__ hcarry)
{
    const int idx = blockIdx.x * 256 + threadIdx.x;  // b*32768 + n*2048 + d
    if (idx >= BB_ * NST * DIN) return;
    const int d = idx & (DIN - 1);
    const int n = (idx >> 11) & 15;
    const int b = idx >> 15;
    const float A2 = A2t[n * DIN + d];
    float h = 0.f;
    for (int c = 0; c < NCHUNK; ++c) {
        const int cb = b * NCHUNK + c;
        const size_t off = ((size_t)cb * NST + n) * DIN + d;
        const float he = hcarry[off];
        const float pa = __expf(A2 * sdtbuf[(size_t)cb * DIN + d]);
        hcarry[off] = h;
        h = fmaf(pa, h, he);
    }
}

__global__ __launch_bounds__(256) void scan_phase_c(
    const u16* __restrict__ dt, const u16* __restrict__ u,
    const float* __restrict__ dtBC, const float* __restrict__ A2t,
    const float* __restrict__ hinit, const float* __restrict__ Dp,
    u16* __restrict__ ysb)
{
    const int d = blockIdx.x * 256 + threadIdx.x;
    const int c = blockIdx.y;
    const int b = blockIdx.z;

    __shared__ float Bs[CLEN][NST];
    __shared__ float Cs[CLEN][NST];
    for (int e = threadIdx.x; e < CLEN * NST; e += 256) {
        const int tl = e >> 4, n = e & 15;
        const size_t base = (size_t)(b * LL + c * CLEN + tl) * 96;
        Bs[tl][n] = dtBC[base + 64 + n];
        Cs[tl][n] = dtBC[base + 80 + n];
    }
    __syncthreads();

    float A2r[NST], h[NST];
    const int cb = b * NCHUNK + c;
    #pragma unroll
    for (int n = 0; n < NST; ++n) {
        A2r[n] = A2t[n * DIN + d];
        h[n]   = hinit[((size_t)cb * NST + n) * DIN + d];
    }
    const float Dv = Dp[d];

    const size_t tbase = (size_t)(b * LL + c * CLEN) * DIN + d;
    for (int tl = 0; tl < CLEN; ++tl) {
        const float dtv = bf2f(dt[tbase + (size_t)tl * DIN]);
        const float uv  = bf2f(u [tbase + (size_t)tl * DIN]);
        const float cu = dtv * uv;
        float yacc = 0.f;
        #pragma unroll
        for (int n = 0; n < NST; ++n) {
            const float a = __expf(A2r[n] * dtv);
            h[n] = fmaf(a, h[n], cu * Bs[tl][n]);
            yacc = fmaf(h[n], Cs[tl][n], yacc);
        }
        ysb[tbase + (size_t)tl * DIN] = f2bf(fmaf(Dv, uv, yacc));
    }
}

// ---------------- launcher ----------------
extern "C" void kernel_launch(void* const* d_in, const int* in_sizes, int n_in,
                              void* d_out, int out_size, void* d_ws, size_t ws_size,
                              hipStream_t stream)
{
    const float* x       = (const float*)d_in[0];
    const float* in_g1   = (const float*)d_in[1];
    const float* in_g2   = (const float*)d_in[2];
    const float* x_g1    = (const float*)d_in[3];
    const float* x_g2    = (const float*)d_in[4];
    const float* dt_g1   = (const float*)d_in[5];
    const float* dt_g2   = (const float*)d_in[6];
    const float* out_g1  = (const float*)d_in[7];
    const float* out_g2  = (const float*)d_in[8];
    const float* filt    = (const float*)d_in[9];
    const float* bias    = (const float*)d_in[10];
    const float* A_log   = (const float*)d_in[11];
    const float* Dp      = (const float*)d_in[12];

    float* ws     = (float*)d_ws;
    u16*   W_inT  = (u16*)(ws + OFF_WINT);
    u16*   W_outT = (u16*)(ws + OFF_WOUTT);
    u16*   W_xT   = (u16*)(ws + OFF_WXT);
    u16*   W_dtT  = (u16*)(ws + OFF_WDTT);
    float* A2t    = ws + OFF_A2T;
    u16*   xb     = (u16*)(ws + OFF_XB);
    u16*   xzb    = (u16*)(ws + OFF_XZB);
    u16*   yb     = (u16*)(ws + OFF_YB);
    float* part   = ws + OFF_PART;
    float* dtBC   = ws + OFF_DTBC;
    u16*   dtun_b = (u16*)(ws + OFF_DTUNB);
    u16*   dtb    = (u16*)(ws + OFF_DTB);
    u16*   ysb    = (u16*)(ws + OFF_YSB);
    float* hc     = ws + OFF_HC;
    float* sdt    = ws + OFF_SDT;
    float* part4  = ws + OFF_PART4;

    // 1) all prep in one launch: W_inT, W_outT, W_xT, W_dtT, x->bf16, A2t
    mega_prep<<<4800, 256, 0, stream>>>(
        in_g1, in_g2, W_inT, out_g1, out_g2, W_outT,
        x_g1, x_g2, W_xT, dt_g1, dt_g2, W_dtT,
        x, xb, A_log, A2t);

    // 2) xz = x @ W_in  (M=2048, N=4096, K=1024) -> bf16 (deep-pipelined)
    gemm_bf16_dp<<<dim3(16, 16, 1), 512, 0, stream>>>(
        xb, W_inT, xzb, EE, 4096);

    // 3) y = silu(conv(xc) + bias) * z  -> bf16, 2 tokens/thread rolling window
    conv_gate<<<(BL / 2) * (DIN / 8) / 256, 256, 0, stream>>>(xzb, filt, bias, yb);

    // 4) dtBC partials = y @ W_x (M=2048, N=128->96, K=2048), split-K z=8, BN=64
    gemm_bf16<64, 64, 0><<<dim3(2, 16, 8), 256, 0, stream>>>(
        yb, W_xT, part, DIN, 96, 256, (size_t)BL * 96, 96);
    reduce_dtbc<<<(BL * 96 + 255) / 256, 256, 0, stream>>>(part, dtBC, dtun_b);

    // 5) dt = softplus(dt_un @ W_dt) (M=2048, N=2048, K=64) -> bf16
    gemm_bf16<64, 64, 2><<<dim3(32, 16, 1), 256, 0, stream>>>(
        dtun_b, W_dtT, dtb, 64, DIN, 64, 0, DIN);

    // 6) SSM chunked scan, NCHUNK=32 (512 blocks = 2/CU)
    scan_phase_a<<<dim3(DIN / 256, NCHUNK, BB_), 256, 0, stream>>>(dtb, yb, dtBC, A2t, hc, sdt);
    scan_phase_b<<<(BB_ * NST * DIN) / 256, 256, 0, stream>>>(A2t, sdt, hc);
    scan_phase_c<<<dim3(DIN / 256, NCHUNK, BB_), 256, 0, stream>>>(dtb, yb, dtBC, A2t, hc, Dp, ysb);

    // 7) out = ssm @ W_out (M=2048, N=1024, K=2048), split-K z=4, BN=128
    //    (8,16,4) = 512 blocks = 2/CU; 128-wide tile class runs ~2x the 64-wide
    //    MFMA rate [guide tile-space]; partial traffic 16->33.5 MB is the cost.
    gemm_bf16<128, 64, 0><<<dim3(8, 16, 4), 256, 0, stream>>>(
        ysb, W_outT, part4, DIN, EE, 512, (size_t)BL * EE, EE);
    reduce_out<<<(BL * EE / 4) / 256, 256, 0, stream>>>(part4, (float*)d_out);
}